// Round 3
// baseline (3398.471 us; speedup 1.0000x reference)
//
#include <hip/hip_runtime.h>
#include <math.h>

#define DEV __device__ __forceinline__

typedef __attribute__((ext_vector_type(8))) short short8;
typedef __attribute__((ext_vector_type(4))) short short4v;
typedef __attribute__((ext_vector_type(4))) float f32x4;
typedef __attribute__((ext_vector_type(8))) __bf16 bf16x8;

DEV float bf2f(unsigned short u) {
    union { unsigned int i; float f; } c; c.i = ((unsigned int)u) << 16; return c.f;
}
DEV unsigned short f2bf(float f) {
    union { float f; unsigned int i; } c; c.f = f;
    unsigned int u = c.i;
    u += 0x7fffu + ((u >> 16) & 1u);   // RNE
    return (unsigned short)(u >> 16);
}
DEV float gelu_exact(float x) { return 0.5f * x * (1.0f + erff(x * 0.70710678118654752f)); }

#define GLL16(g, l)                                                                   \
    __builtin_amdgcn_global_load_lds(                                                \
        (const __attribute__((address_space(1))) unsigned int*)(g),                  \
        (__attribute__((address_space(3))) unsigned int*)(l), 16, 0, 0)

// ---------------------------------------------------------------------------
// Weight transpose + f32->bf16 convert: in (K,N) f32 row-major -> out (N,K) bf16.
// ---------------------------------------------------------------------------
__global__ __launch_bounds__(256)
void transpose_w(const float* __restrict__ in, unsigned short* __restrict__ out,
                 const float* __restrict__ rowscale, float uscale,
                 int K, int N, size_t inStride, size_t outStride, int scaleStride)
{
    __shared__ float tile[64][65];
    in  += (size_t)blockIdx.z * inStride;
    out += (size_t)blockIdx.z * outStride;
    const int k0 = blockIdx.y * 64, n0 = blockIdx.x * 64;
    const int tid = threadIdx.x;
    const int c = tid & 63;
#pragma unroll
    for (int i = 0; i < 16; ++i) {
        int rr = (i << 2) + (tid >> 6);
        float v = in[(size_t)(k0 + rr) * N + n0 + c];
        if (rowscale) v *= rowscale[(size_t)blockIdx.z * scaleStride + k0 + rr];
        tile[rr][c] = v * uscale;
    }
    __syncthreads();
#pragma unroll
    for (int i = 0; i < 16; ++i) {
        int rr = (i << 2) + (tid >> 6);
        out[(size_t)(n0 + rr) * K + k0 + c] = f2bf(tile[c][rr]);
    }
}

// bias_kv[d][c] = sum_r ln_media_b[d][r] * w[d][r][c]
__global__ __launch_bounds__(256)
void fold_bias(const float* __restrict__ wk, const float* __restrict__ wv,
               const float* __restrict__ bmed, float* __restrict__ biaskv)
{
    const int d = blockIdx.x >> 3;
    const int rem = blockIdx.x & 7;
    const int part = rem >> 2;
    const int chunk = rem & 3;
    const float* w = (part ? wv : wk) + (size_t)d * 1024 * 1024 + chunk * 256 + threadIdx.x;
    const float* b = bmed + d * 1024;
    float acc = 0.f;
    for (int r = 0; r < 1024; ++r) acc += b[r] * w[(size_t)r * 1024];
    biaskv[d * 2048 + part * 1024 + chunk * 256 + threadIdx.x] = acc;
}

__global__ __launch_bounds__(256)
void convert_bf16(const float* __restrict__ in, unsigned short* __restrict__ out, size_t n4)
{
    size_t i = (size_t)blockIdx.x * 256 + threadIdx.x;
    if (i >= n4) return;
    float4 v = ((const float4*)in)[i];
    ushort4 u;
    u.x = f2bf(v.x); u.y = f2bf(v.y); u.z = f2bf(v.z); u.w = f2bf(v.w);
    ((ushort4*)out)[i] = u;
}

__global__ __launch_bounds__(256)
void init_x(const float* __restrict__ lat, float* __restrict__ x)
{
    const int row = blockIdx.x;
    ((float4*)x)[(size_t)row * 256 + threadIdx.x] =
        ((const float4*)lat)[(size_t)(row & 255) * 256 + threadIdx.x];
}

// ---------------------------------------------------------------------------
// LayerNorm over D=1024, one row per block.
// ---------------------------------------------------------------------------
template<bool AFFINE, bool OUTBF>
__global__ __launch_bounds__(256)
void ln_k(const float* __restrict__ in, const float* __restrict__ g,
          const float* __restrict__ b, void* __restrict__ out)
{
    const int row = blockIdx.x;
    const int tid = threadIdx.x;
    float4 v = ((const float4*)(in + (size_t)row * 1024))[tid];
    float s  = v.x + v.y + v.z + v.w;
    float ss = v.x * v.x + v.y * v.y + v.z * v.z + v.w * v.w;
#pragma unroll
    for (int o = 32; o > 0; o >>= 1) { s += __shfl_down(s, o); ss += __shfl_down(ss, o); }
    __shared__ float red[8];
    if ((tid & 63) == 0) { red[tid >> 6] = s; red[4 + (tid >> 6)] = ss; }
    __syncthreads();
    const float sum  = red[0] + red[1] + red[2] + red[3];
    const float ssum = red[4] + red[5] + red[6] + red[7];
    const float mean = sum * (1.0f / 1024.0f);
    const float var  = ssum * (1.0f / 1024.0f) - mean * mean;
    const float rs   = rsqrtf(var + 1e-5f);
    float o0 = (v.x - mean) * rs, o1 = (v.y - mean) * rs;
    float o2 = (v.z - mean) * rs, o3 = (v.w - mean) * rs;
    if (AFFINE) {
        float4 gv = ((const float4*)g)[tid];
        float4 bv = ((const float4*)b)[tid];
        o0 = o0 * gv.x + bv.x; o1 = o1 * gv.y + bv.y;
        o2 = o2 * gv.z + bv.z; o3 = o3 * gv.w + bv.w;
    }
    if (OUTBF) {
        ushort4 u; u.x = f2bf(o0); u.y = f2bf(o1); u.z = f2bf(o2); u.w = f2bf(o3);
        ((ushort4*)out)[(size_t)row * 256 + tid] = u;
    } else {
        float4 ov; ov.x = o0; ov.y = o1; ov.z = o2; ov.w = o3;
        ((float4*)out)[(size_t)row * 256 + tid] = ov;
    }
}

enum { E_BF16 = 0, E_BIAS_BF16, E_BIAS_GELU_BF16, E_BIAS_TPOS_F32, E_ADD_F32, E_BIAS_ADD_F32 };

// ---------------------------------------------------------------------------
// Big-shape GEMM v2: 256x256 tile, BK=32, 8 waves (2Mx4N), 4-deep LDS ring,
// T2 XOR-swizzle (pre-swizzled global source + swizzled read, rule #21),
// m201 phase skeleton (barrier/lgkmcnt(0)/setprio around 16-MFMA clusters),
// counted vmcnt at tile boundary (T3/T4), XCD swizzle (T1),
// LDS-transpose coalesced epilogue.
// C(M,N) = A(M,K) @ Bt(N,K)^T.  Requires M%256==0, N%256==0, K%32==0, K/32>=4.
// ---------------------------------------------------------------------------
template<int EPI>
__global__ __launch_bounds__(512, 2)
void gemm256(const unsigned short* __restrict__ A, const unsigned short* __restrict__ Bt,
             void* __restrict__ Out,
             const float* __restrict__ bias, const float* __restrict__ tpos,
             int M, int N, int K)
{
    __shared__ unsigned short sm[4][2][8192];   // 4 bufs x (A,B) x 256rows x 32k = 128 KiB

    const int tid  = threadIdx.x;
    const int wid  = tid >> 6, lane = tid & 63;
    const int wm   = wid >> 2, wn = wid & 3;

    // T1: bijective XCD swizzle (all grids here are multiples of 8)
    const int nbx = N >> 8;
    const int nwg = gridDim.x;
    int i = blockIdx.x;
    int wg = ((nwg & 7) == 0) ? ((i & 7) * (nwg >> 3) + (i >> 3)) : i;
    const int by = wg / nbx, bx = wg % nbx;

    const int nt = K >> 5;

    // staging: thread covers physical LDS slot (row = tid>>2, qp = tid&3);
    // logical k-quarter there is qp ^ sel(row), sel(row) = (row>>1)&3 = (tid>>3)&3.
    const int schunk = (tid & 3) ^ ((tid >> 3) & 3);
    const unsigned short* gA = A  + (size_t)(by * 256 + (tid >> 2)) * K + schunk * 8;
    const unsigned short* gB = Bt + (size_t)(bx * 256 + (tid >> 2)) * K + schunk * 8;
    const int wbase = wid * 512;     // wave-uniform LDS base (u16 units)

    // read-side swizzled k-quarter: q' = (lane>>4) ^ ((row>>1)&3), row bits1-2 = lane bits1-2
    const int qsw  = ((lane >> 4) ^ ((lane >> 1) & 3)) * 8;
    const int aoff = (wm * 128 + (lane & 15)) * 32 + qsw;
    const int boff = (wn * 64  + (lane & 15)) * 32 + qsw;

    f32x4 acc[8][4] = {};

    // prologue: stage tiles 0,1,2 ; certify tile 0
    for (int pt = 0; pt < 3; ++pt) {
        const unsigned short* ga = gA + (size_t)pt * 32;
        const unsigned short* gb = gB + (size_t)pt * 32;
        GLL16(ga,                   &sm[pt][0][wbase]);
        GLL16(ga + (size_t)128 * K, &sm[pt][0][wbase + 4096]);
        GLL16(gb,                   &sm[pt][1][wbase]);
        GLL16(gb + (size_t)128 * K, &sm[pt][1][wbase + 4096]);
    }
    asm volatile("s_waitcnt vmcnt(8)" ::: "memory");
    asm volatile("s_barrier" ::: "memory");

    for (int t = 0; t < nt; ++t) {
        const int cur = t & 3;
        const int st  = t + 3;
        const bool stg = st < nt;
        const int sb  = st & 3;

        const unsigned short* la = &sm[cur][0][0] + aoff;
        const unsigned short* lb = &sm[cur][1][0] + boff;

        bf16x8 aA[4], aB[4], b[4];

        // ================= PHASE A =================
#pragma unroll
        for (int mi = 0; mi < 4; ++mi) aA[mi] = *(const bf16x8*)(la + mi * 512);
#pragma unroll
        for (int ni = 0; ni < 4; ++ni) b[ni] = *(const bf16x8*)(lb + ni * 512);
        if (stg) {
            const unsigned short* ga = gA + (size_t)st * 32;
            GLL16(ga,                   &sm[sb][0][wbase]);
            GLL16(ga + (size_t)128 * K, &sm[sb][0][wbase + 4096]);
        }
        asm volatile("s_barrier" ::: "memory");
        asm volatile("s_waitcnt lgkmcnt(0)" ::: "memory");
        __builtin_amdgcn_sched_barrier(0);
        __builtin_amdgcn_s_setprio(1);
#pragma unroll
        for (int mi = 0; mi < 4; ++mi)
#pragma unroll
            for (int ni = 0; ni < 4; ++ni)
                acc[mi][ni] = __builtin_amdgcn_mfma_f32_16x16x32_bf16(aA[mi], b[ni], acc[mi][ni], 0, 0, 0);
        __builtin_amdgcn_s_setprio(0);
        asm volatile("s_barrier" ::: "memory");

        // ================= PHASE B =================
#pragma unroll
        for (int mi = 0; mi < 4; ++mi) aB[mi] = *(const bf16x8*)(la + (mi + 4) * 512);
        if (stg) {
            const unsigned short* gb = gB + (size_t)st * 32;
            GLL16(gb,                   &sm[sb][1][wbase]);
            GLL16(gb + (size_t)128 * K, &sm[sb][1][wbase + 4096]);
        }
        asm volatile("s_barrier" ::: "memory");
        asm volatile("s_waitcnt lgkmcnt(0)" ::: "memory");
        __builtin_amdgcn_sched_barrier(0);
        __builtin_amdgcn_s_setprio(1);
#pragma unroll
        for (int mi = 0; mi < 4; ++mi)
#pragma unroll
            for (int ni = 0; ni < 4; ++ni)
                acc[mi + 4][ni] = __builtin_amdgcn_mfma_f32_16x16x32_bf16(aB[mi], b[ni], acc[mi + 4][ni], 0, 0, 0);
        __builtin_amdgcn_s_setprio(0);

        // ---- boundary: certify tile t+1 (counted vmcnt, never 0 mid-loop) ----
        if (t + 1 < nt) {
            __builtin_amdgcn_sched_barrier(0);
            const int staged_last = stg ? st : (nt - 1);
            const int ahead = staged_last - (t + 1);
            if (ahead >= 2)      asm volatile("s_waitcnt vmcnt(8)" ::: "memory");
            else if (ahead == 1) asm volatile("s_waitcnt vmcnt(4)" ::: "memory");
            else                 asm volatile("s_waitcnt vmcnt(0)" ::: "memory");
            asm volatile("s_barrier" ::: "memory");
        }
    }

    // ================= EPILOGUE (LDS transpose -> coalesced stores) =========
    // C/D frag layout: col = lane&15, row = (lane>>4)*4 + j  [m89-verified]
    __syncthreads();   // all LDS reads of the main loop done; safe to reuse sm
    const int q    = lane >> 4;
    const int lcw  = wn * 64 + (lane & 15);          // writer logical col (+ni*16)
    const int rowW = wm * 16 + q * 4;                // writer local row (+j)
    const int rLr  = tid >> 4;                       // reader local row 0..31
    const int rqs  = ((rLr & 15) >> 2) << 4;         // reader un-swizzle (q<<4)
    const int gRr  = by * 256 + (rLr >> 4) * 128 + (rLr & 15);  // + mi*16
    if (EPI == E_BIAS_TPOS_F32) {
        float* sf = (float*)&sm[0][0][0];            // [32][256] f32 = 32 KiB
        const int rC = (tid & 15) * 16;              // reader logical col base
        for (int mi = 0; mi < 8; ++mi) {
#pragma unroll
            for (int ni = 0; ni < 4; ++ni) {
                const int c  = lcw + ni * 16;
                const int cx = c ^ (q << 4);
                const float bv = bias[bx * 256 + c];
#pragma unroll
                for (int j = 0; j < 4; ++j) {
                    const int gr = by * 256 + wm * 128 + mi * 16 + q * 4 + j;
                    float v = acc[mi][ni][j] + bv + tpos[(((unsigned)gr >> 8) & 15) * 1024 + bx * 256 + c];
                    sf[(rowW + j) * 256 + cx] = v;
                }
            }
            __syncthreads();
            {
                const int gr = gRr + mi * 16;
                float* dst = (float*)Out + (size_t)gr * N + bx * 256 + rC;
#pragma unroll
                for (int cchunk = 0; cchunk < 4; ++cchunk) {
                    const int cl = rC + cchunk * 4;
                    float4 v = *(const float4*)&sf[rLr * 256 + (cl ^ rqs)];
                    *(float4*)&dst[cchunk * 4] = v;
                }
            }
            __syncthreads();
        }
    } else {
        unsigned short* s16 = (unsigned short*)&sm[0][0][0];   // [32][256] u16 = 16 KiB
        const int rC = (tid & 15) * 16;
        for (int mi = 0; mi < 8; ++mi) {
#pragma unroll
            for (int ni = 0; ni < 4; ++ni) {
                const int c  = lcw + ni * 16;
                const int cx = c ^ (q << 4);
                float bv = 0.f;
                if (EPI == E_BIAS_BF16 || EPI == E_BIAS_GELU_BF16) bv = bias[bx * 256 + c];
#pragma unroll
                for (int j = 0; j < 4; ++j) {
                    float v = acc[mi][ni][j] + bv;
                    if (EPI == E_BIAS_GELU_BF16) v = gelu_exact(v);
                    s16[(rowW + j) * 256 + cx] = f2bf(v);
                }
            }
            __syncthreads();
            {
                const int gr = gRr + mi * 16;
                unsigned short* dst = (unsigned short*)Out + (size_t)gr * N + bx * 256 + rC;
                short8 v0 = *(const short8*)&s16[rLr * 256 + (rC ^ rqs)];
                short8 v1 = *(const short8*)&s16[rLr * 256 + ((rC + 8) ^ rqs)];
                *(short8*)&dst[0] = v0;
                *(short8*)&dst[8] = v1;
            }
            __syncthreads();
        }
    }
}

// ---------------------------------------------------------------------------
// Small-shape GEMM (m97 structure, 128x128, BK=64) for M=2048 layers.
// ---------------------------------------------------------------------------
template<int EPI>
__global__ __launch_bounds__(256, 2)
void gemm_bt(const unsigned short* __restrict__ A, const unsigned short* __restrict__ Bt,
             void* __restrict__ Out,
             const float* __restrict__ bias, const float* __restrict__ addsrc,
             const float* __restrict__ tpos,
             int M, int N, int K)
{
    __shared__ unsigned short lds[2 * 128 * 64];
    const int tid  = threadIdx.x;
    const int wave = tid >> 6, lane = tid & 63;
    const int nbx  = N >> 7;
    const int by   = blockIdx.x / nbx, bx = blockIdx.x % nbx;

    const unsigned short* gA = A  + (size_t)(by * 128 + (lane >> 3)) * K + ((lane & 7) * 8);
    const unsigned short* gB = Bt + (size_t)(bx * 128 + (lane >> 3)) * K + ((lane & 7) * 8);

    const int wr = wave >> 1, wc = wave & 1;
    f32x4 acc[4][4] = {};

    unsigned short* ldsA = lds;
    unsigned short* ldsB = lds + 128 * 64;

    for (int kt = 0; kt < K; kt += 64) {
#pragma unroll
        for (int j = 0; j < 4; ++j) {
            const int chunk = (j << 2) + wave;
            GLL16(gA + (size_t)chunk * 8 * K + kt, ldsA + chunk * 512);
            GLL16(gB + (size_t)chunk * 8 * K + kt, ldsB + chunk * 512);
        }
        __syncthreads();
        const unsigned short* la = ldsA + (wr * 64 + (lane & 15)) * 64 + (lane >> 4) * 8;
        const unsigned short* lb = ldsB + (wc * 64 + (lane & 15)) * 64 + (lane >> 4) * 8;
#pragma unroll
        for (int kk = 0; kk < 2; ++kk) {
            bf16x8 a[4], b[4];
#pragma unroll
            for (int m = 0; m < 4; ++m) a[m] = *(const bf16x8*)(la + m * 16 * 64 + kk * 32);
#pragma unroll
            for (int n = 0; n < 4; ++n) b[n] = *(const bf16x8*)(lb + n * 16 * 64 + kk * 32);
#pragma unroll
            for (int m = 0; m < 4; ++m)
#pragma unroll
                for (int n = 0; n < 4; ++n)
                    acc[m][n] = __builtin_amdgcn_mfma_f32_16x16x32_bf16(a[m], b[n], acc[m][n], 0, 0, 0);
        }
        __syncthreads();
    }

    const int r0 = by * 128 + wr * 64 + (lane >> 4) * 4;
    const int c0 = bx * 128 + wc * 64 + (lane & 15);
#pragma unroll
    for (int m = 0; m < 4; ++m) {
#pragma unroll
        for (int n = 0; n < 4; ++n) {
            const int c = c0 + n * 16;
#pragma unroll
            for (int j = 0; j < 4; ++j) {
                const int r = r0 + m * 16 + j;
                float v = acc[m][n][j];
                if (EPI == E_BIAS_BF16 || EPI == E_BIAS_GELU_BF16 ||
                    EPI == E_BIAS_TPOS_F32 || EPI == E_BIAS_ADD_F32)
                    v += bias[c];
                if (EPI == E_BIAS_GELU_BF16) v = gelu_exact(v);
                if (EPI == E_BIAS_TPOS_F32)  v += tpos[(((unsigned)r >> 8) & 15) * 1024 + c];
                if (EPI == E_ADD_F32 || EPI == E_BIAS_ADD_F32) v += addsrc[(size_t)r * N + c];
                if (EPI == E_BIAS_TPOS_F32 || EPI == E_ADD_F32 || EPI == E_BIAS_ADD_F32)
                    ((float*)Out)[(size_t)r * N + c] = v;
                else
                    ((unsigned short*)Out)[(size_t)r * N + c] = f2bf(v);
            }
        }
    }
}

// ---------------------------------------------------------------------------
// Attention: one block per (bt, head). Q=16, F=272, DH=64.
// ---------------------------------------------------------------------------
__global__ __launch_bounds__(256)
void attn_k(const unsigned short* __restrict__ qkvl, const unsigned short* __restrict__ kvm,
            unsigned short* __restrict__ o)
{
    __shared__ unsigned short kv[272 * 72];
    __shared__ float sim[16 * 273];
    __shared__ float qs[16 * 68];
    __shared__ float red[64];

    const int bt = blockIdx.x >> 4, h = blockIdx.x & 15;
    const int tid = threadIdx.x;
    const int lane = tid & 63, wave = tid >> 6;
    const int r = tid & 15, grp = tid >> 4;

    {
        const int qi = tid >> 4, d0 = (tid & 15) * 4;
        const unsigned short* src = qkvl + (size_t)(bt * 16 + qi) * 3072 + h * 64 + d0;
        qs[qi * 68 + d0 + 0] = bf2f(src[0]);
        qs[qi * 68 + d0 + 1] = bf2f(src[1]);
        qs[qi * 68 + d0 + 2] = bf2f(src[2]);
        qs[qi * 68 + d0 + 3] = bf2f(src[3]);
    }
#pragma unroll
    for (int i = 0; i < 9; ++i) {
        int idx = i * 256 + tid;
        if (idx < 2176) {
            int f = idx >> 3, cp = idx & 7;
            const unsigned short* src = (f < 256)
                ? kvm  + (size_t)(bt * 256 + f) * 2048 + h * 64 + cp * 8
                : qkvl + (size_t)(bt * 16 + (f - 256)) * 3072 + 1024 + h * 64 + cp * 8;
            *(short8*)&kv[f * 72 + cp * 8] = *(const short8*)src;
        }
    }
    __syncthreads();

    float p[17];
#pragma unroll
    for (int i = 0; i < 17; ++i) p[i] = 0.f;
#pragma unroll
    for (int d = 0; d < 64; d += 8) {
        float q8[8];
#pragma unroll
        for (int j = 0; j < 8; ++j) q8[j] = qs[r * 68 + d + j];
#pragma unroll
        for (int i = 0; i < 17; ++i) {
            short8 k8 = *(const short8*)&kv[(grp + i * 16) * 72 + d];
#pragma unroll
            for (int j = 0; j < 8; ++j) p[i] += q8[j] * bf2f((unsigned short)k8[j]);
        }
    }
    float mx = -3.0e38f;
#pragma unroll
    for (int i = 0; i < 17; ++i) mx = fmaxf(mx, p[i]);
    mx = fmaxf(mx, __shfl_xor(mx, 16));
    mx = fmaxf(mx, __shfl_xor(mx, 32));
    if (lane < 16) red[wave * 16 + lane] = mx;
    __syncthreads();
    const float rowmax = fmaxf(fmaxf(red[r], red[16 + r]), fmaxf(red[32 + r], red[48 + r]));

    float sm = 0.f;
#pragma unroll
    for (int i = 0; i < 17; ++i) { p[i] = __expf(p[i] - rowmax); sm += p[i]; }
    sm += __shfl_xor(sm, 16);
    sm += __shfl_xor(sm, 32);
#pragma unroll
    for (int i = 0; i < 17; ++i) sim[r * 273 + grp + i * 16] = p[i];
    __syncthreads();
    if (lane < 16) red[wave * 16 + lane] = sm;
#pragma unroll
    for (int i = 0; i < 9; ++i) {
        int idx = i * 256 + tid;
        if (idx < 2176) {
            int f = idx >> 3, cp = idx & 7;
            const unsigned short* src = (f < 256)
                ? kvm  + (size_t)(bt * 256 + f) * 2048 + 1024 + h * 64 + cp * 8
                : qkvl + (size_t)(bt * 16 + (f - 256)) * 3072 + 2048 + h * 64 + cp * 8;
            *(short8*)&kv[f * 72 + cp * 8] = *(const short8*)src;
        }
    }
    __syncthreads();
    const float inv = 1.0f / (red[r] + red[16 + r] + red[32 + r] + red[48 + r]);

    float o0 = 0.f, o1 = 0.f, o2 = 0.f, o3 = 0.f;
    for (int f = 0; f < 272; ++f) {
        float pv = sim[r * 273 + f];
        short4v v4 = *(const short4v*)&kv[f * 72 + grp * 4];
        o0 += pv * bf2f((unsigned short)v4[0]);
        o1 += pv * bf2f((unsigned short)v4[1]);
        o2 += pv * bf2f((unsigned short)v4[2]);
        o3 += pv * bf2f((unsigned short)v4[3]);
    }
    unsigned short* dst = o + (size_t)(bt * 16 + r) * 1024 + h * 64 + grp * 4;
    dst[0] = f2bf(o0 * inv);
    dst[1] = f2bf(o1 * inv);
    dst[2] = f2bf(o2 * inv);
    dst[3] = f2bf(o3 * inv);
}

// ---------------------------------------------------------------------------
extern "C" void kernel_launch(void* const* d_in, const int* in_sizes, int n_in,
                              void* d_out, int out_size, void* d_ws, size_t ws_size,
                              hipStream_t stream)
{
    const float* x_f      = (const float*)d_in[0];
    const float* goal_w1  = (const float*)d_in[1];
    const float* goal_b1  = (const float*)d_in[2];
    const float* goal_w2  = (const float*)d_in[3];
    const float* goal_b2  = (const float*)d_in[4];
    const float* latents  = (const float*)d_in[5];
    const float* tpos     = (const float*)d_in[6];
    const float* lnm_g    = (const float*)d_in[7];
    const float* lnm_b    = (const float*)d_in[8];
    const float* lnl_g    = (const float*)d_in[9];
    const float* lnl_b    = (const float*)d_in[10];
    const float* wq       = (const float*)d_in[11];
    const float* wk       = (const float*)d_in[12];
    const float* wv       = (const float*)d_in[13];
    const float* wo       = (const float*)d_in[14];
    const float* ffn_g    = (const float*)d_in[15];
    const float* ffn_b    = (const float*)d_in[16];
    const float* ffw1     = (const float*)d_in[17];
    const float* ffb1     = (const float*)d_in[18];
    const float* ffw2     = (const float*)d_in[19];
    const float* ffb2     = (const float*)d_in[20];
    const float* fin_g    = (const float*)d_in[21];
    const float* fin_b    = (const float*)d_in[22];

    char* ws = (char*)d_ws;
    size_t off = 0;
    auto alloc = [&](size_t bytes) -> char* {
        char* p = ws + off;
        off += (bytes + 255) & ~(size_t)255;
        return p;
    };
    typedef unsigned short u16;
    u16*   wg1t   = (u16*)  alloc(2048ull * 1280 * 2);
    u16*   wg2t   = (u16*)  alloc(1024ull * 2048 * 2);
    u16*   wqkvl  = (u16*)  alloc(6ull * 3072 * 1024 * 2);
    u16*   wkvm   = (u16*)  alloc(6ull * 2048 * 1024 * 2);
    u16*   wot    = (u16*)  alloc(6ull * 1024 * 1024 * 2);
    u16*   wf1t   = (u16*)  alloc(6ull * 4096 * 1024 * 2);
    u16*   wf2t   = (u16*)  alloc(6ull * 1024 * 4096 * 2);
    float* biaskv = (float*)alloc(6ull * 2048 * 4);
    float* xres   = (float*)alloc(2048ull * 1024 * 4);
    u16*   latn   = (u16*)  alloc(2048ull * 1024 * 2);
    u16*   qkvl   = (u16*)  alloc(2048ull * 3072 * 2);
    u16*   obuf   = (u16*)  alloc(2048ull * 1024 * 2);
    u16*   ffny   = (u16*)  alloc(2048ull * 1024 * 2);
    u16*   ffnmid = (u16*)  alloc(2048ull * 4096 * 2);
    u16*   bufA   = (u16*)  alloc(32768ull * 2048 * 2);
    float* bufB   = (float*)alloc(32768ull * 1024 * 4);
    u16*   bufC   = (u16*)  alloc(41943040ull * 2);
    if (off > ws_size) return;

    // ---- phase 0: conversions / folds ----
    convert_bf16<<<40960, 256, 0, stream>>>(x_f, bufC, 41943040ull / 4);
    transpose_w<<<dim3(32, 20, 1), 256, 0, stream>>>(goal_w1, wg1t, nullptr, 1.f, 1280, 2048, 0, 0, 0);
    transpose_w<<<dim3(16, 32, 1), 256, 0, stream>>>(goal_w2, wg2t, nullptr, 1.f, 2048, 1024, 0, 0, 0);
    transpose_w<<<dim3(16, 16, 6), 256, 0, stream>>>(wq, wqkvl,                nullptr, 0.125f, 1024, 1024, 1024ull*1024, 3072ull*1024, 0);
    transpose_w<<<dim3(16, 16, 6), 256, 0, stream>>>(wk, wqkvl + 1024ull*1024, nullptr, 1.f,    1024, 1024, 1024ull*1024, 3072ull*1024, 0);
    transpose_w<<<dim3(16, 16, 6), 256, 0, stream>>>(wv, wqkvl + 2048ull*1024, nullptr, 1.f,    1024, 1024, 1024ull*1024, 3072ull*1024, 0);
    transpose_w<<<dim3(16, 16, 6), 256, 0, stream>>>(wk, wkvm,                 lnm_g,   1.f,    1024, 1024, 1024ull*1024, 2048ull*1024, 1024);
    transpose_w<<<dim3(16, 16, 6), 256, 0, stream>>>(wv, wkvm + 1024ull*1024,  lnm_g,   1.f,    1024, 1024, 1024ull*1024, 2048ull*1024, 1024);
    transpose_w<<<dim3(16, 16, 6), 256, 0, stream>>>(wo, wot,                  nullptr, 1.f,    1024, 1024, 1024ull*1024, 1024ull*1024, 0);
    transpose_w<<<dim3(64, 16, 6), 256, 0, stream>>>(ffw1, wf1t,               nullptr, 1.f,    1024, 4096, 4096ull*1024, 4096ull*1024, 0);
    transpose_w<<<dim3(16, 64, 6), 256, 0, stream>>>(ffw2, wf2t,               nullptr, 1.f,    4096, 1024, 4096ull*1024, 4096ull*1024, 0);
    fold_bias<<<48, 256, 0, stream>>>(wk, wv, lnm_b, biaskv);
    init_x<<<2048, 256, 0, stream>>>(latents, xres);

    // ---- goal MLP (big GEMMs -> gemm256) ----
    gemm256<E_BIAS_GELU_BF16><<<128 * 8, 512, 0, stream>>>(bufC, wg1t, bufA, goal_b1, nullptr, 32768, 2048, 1280);
    gemm256<E_BIAS_TPOS_F32><<<128 * 4, 512, 0, stream>>>(bufA, wg2t, bufB, goal_b2, tpos, 32768, 1024, 2048);
    ln_k<false, true><<<32768, 256, 0, stream>>>(bufB, nullptr, nullptr, bufC);

    // ---- depth loop ----
    for (int i = 0; i < 6; ++i) {
        const u16* wqkvl_i = wqkvl + (size_t)i * 3072 * 1024;
        const u16* wkvm_i  = wkvm  + (size_t)i * 2048 * 1024;
        const u16* wot_i   = wot   + (size_t)i * 1024 * 1024;
        const u16* wf1_i   = wf1t  + (size_t)i * 4096 * 1024;
        const u16* wf2_i   = wf2t  + (size_t)i * 1024 * 4096;

        ln_k<true, true><<<2048, 256, 0, stream>>>(xres, lnl_g + i * 1024, lnl_b + i * 1024, latn);
        gemm_bt<E_BF16><<<16 * 24, 256, 0, stream>>>(latn, wqkvl_i, qkvl, nullptr, nullptr, nullptr, 2048, 3072, 1024);
        gemm256<E_BIAS_BF16><<<128 * 8, 512, 0, stream>>>(bufC, wkvm_i, bufA, biaskv + i * 2048, nullptr, 32768, 2048, 1024);
        attn_k<<<2048, 256, 0, stream>>>(qkvl, bufA, obuf);
        gemm_bt<E_ADD_F32><<<16 * 8, 256, 0, stream>>>(obuf, wot_i, xres, nullptr, xres, nullptr, 2048, 1024, 1024);
        ln_k<true, true><<<2048, 256, 0, stream>>>(xres, ffn_g + i * 1024, ffn_b + i * 1024, ffny);
        gemm_bt<E_BIAS_GELU_BF16><<<16 * 32, 256, 0, stream>>>(ffny, wf1_i, ffnmid, ffb1 + i * 4096, nullptr, nullptr, 2048, 4096, 1024);
        gemm_bt<E_BIAS_ADD_F32><<<16 * 8, 256, 0, stream>>>(ffnmid, wf2_i, xres, ffb2 + i * 1024, xres, nullptr, 2048, 1024, 4096);
    }

    // ---- final LN -> d_out (f32) ----
    ln_k<true, false><<<2048, 256, 0, stream>>>(xres, fin_g, fin_b, d_out);
}

// Round 4
// 2824.680 us; speedup vs baseline: 1.2031x; 1.2031x over previous
//
#include <hip/hip_runtime.h>
#include <math.h>

#define DEV __device__ __forceinline__

typedef __attribute__((ext_vector_type(8))) short short8;
typedef __attribute__((ext_vector_type(4))) short short4v;
typedef __attribute__((ext_vector_type(4))) float f32x4;
typedef __attribute__((ext_vector_type(8))) __bf16 bf16x8;

DEV float bf2f(unsigned short u) {
    union { unsigned int i; float f; } c; c.i = ((unsigned int)u) << 16; return c.f;
}
DEV unsigned short f2bf(float f) {
    union { float f; unsigned int i; } c; c.f = f;
    unsigned int u = c.i;
    u += 0x7fffu + ((u >> 16) & 1u);   // RNE
    return (unsigned short)(u >> 16);
}
DEV float gelu_exact(float x) { return 0.5f * x * (1.0f + erff(x * 0.70710678118654752f)); }

#define GLL16(g, l)                                                                   \
    __builtin_amdgcn_global_load_lds(                                                \
        (const __attribute__((address_space(1))) unsigned int*)(g),                  \
        (__attribute__((address_space(3))) unsigned int*)(l), 16, 0, 0)

// ---------------------------------------------------------------------------
// Weight transpose + f32->bf16 convert: in (K,N) f32 row-major -> out (N,K) bf16.
// ---------------------------------------------------------------------------
__global__ __launch_bounds__(256)
void transpose_w(const float* __restrict__ in, unsigned short* __restrict__ out,
                 const float* __restrict__ rowscale, float uscale,
                 int K, int N, size_t inStride, size_t outStride, int scaleStride)
{
    __shared__ float tile[64][65];
    in  += (size_t)blockIdx.z * inStride;
    out += (size_t)blockIdx.z * outStride;
    const int k0 = blockIdx.y * 64, n0 = blockIdx.x * 64;
    const int tid = threadIdx.x;
    const int c = tid & 63;
#pragma unroll
    for (int i = 0; i < 16; ++i) {
        int rr = (i << 2) + (tid >> 6);
        float v = in[(size_t)(k0 + rr) * N + n0 + c];
        if (rowscale) v *= rowscale[(size_t)blockIdx.z * scaleStride + k0 + rr];
        tile[rr][c] = v * uscale;
    }
    __syncthreads();
#pragma unroll
    for (int i = 0; i < 16; ++i) {
        int rr = (i << 2) + (tid >> 6);
        out[(size_t)(n0 + rr) * K + k0 + c] = f2bf(tile[c][rr]);
    }
}

// bias_kv[d][c] = sum_r ln_media_b[d][r] * w[d][r][c]
__global__ __launch_bounds__(256)
void fold_bias(const float* __restrict__ wk, const float* __restrict__ wv,
               const float* __restrict__ bmed, float* __restrict__ biaskv)
{
    const int d = blockIdx.x >> 3;
    const int rem = blockIdx.x & 7;
    const int part = rem >> 2;
    const int chunk = rem & 3;
    const float* w = (part ? wv : wk) + (size_t)d * 1024 * 1024 + chunk * 256 + threadIdx.x;
    const float* b = bmed + d * 1024;
    float acc = 0.f;
    for (int r = 0; r < 1024; ++r) acc += b[r] * w[(size_t)r * 1024];
    biaskv[d * 2048 + part * 1024 + chunk * 256 + threadIdx.x] = acc;
}

__global__ __launch_bounds__(256)
void convert_bf16(const float* __restrict__ in, unsigned short* __restrict__ out, size_t n4)
{
    size_t i = (size_t)blockIdx.x * 256 + threadIdx.x;
    if (i >= n4) return;
    float4 v = ((const float4*)in)[i];
    ushort4 u;
    u.x = f2bf(v.x); u.y = f2bf(v.y); u.z = f2bf(v.z); u.w = f2bf(v.w);
    ((ushort4*)out)[i] = u;
}

__global__ __launch_bounds__(256)
void init_x(const float* __restrict__ lat, float* __restrict__ x)
{
    const int row = blockIdx.x;
    ((float4*)x)[(size_t)row * 256 + threadIdx.x] =
        ((const float4*)lat)[(size_t)(row & 255) * 256 + threadIdx.x];
}

// ---------------------------------------------------------------------------
// LayerNorm over D=1024, one row per block.
// ---------------------------------------------------------------------------
template<bool AFFINE, bool OUTBF>
__global__ __launch_bounds__(256)
void ln_k(const float* __restrict__ in, const float* __restrict__ g,
          const float* __restrict__ b, void* __restrict__ out)
{
    const int row = blockIdx.x;
    const int tid = threadIdx.x;
    float4 v = ((const float4*)(in + (size_t)row * 1024))[tid];
    float s  = v.x + v.y + v.z + v.w;
    float ss = v.x * v.x + v.y * v.y + v.z * v.z + v.w * v.w;
#pragma unroll
    for (int o = 32; o > 0; o >>= 1) { s += __shfl_down(s, o); ss += __shfl_down(ss, o); }
    __shared__ float red[8];
    if ((tid & 63) == 0) { red[tid >> 6] = s; red[4 + (tid >> 6)] = ss; }
    __syncthreads();
    const float sum  = red[0] + red[1] + red[2] + red[3];
    const float ssum = red[4] + red[5] + red[6] + red[7];
    const float mean = sum * (1.0f / 1024.0f);
    const float var  = ssum * (1.0f / 1024.0f) - mean * mean;
    const float rs   = rsqrtf(var + 1e-5f);
    float o0 = (v.x - mean) * rs, o1 = (v.y - mean) * rs;
    float o2 = (v.z - mean) * rs, o3 = (v.w - mean) * rs;
    if (AFFINE) {
        float4 gv = ((const float4*)g)[tid];
        float4 bv = ((const float4*)b)[tid];
        o0 = o0 * gv.x + bv.x; o1 = o1 * gv.y + bv.y;
        o2 = o2 * gv.z + bv.z; o3 = o3 * gv.w + bv.w;
    }
    if (OUTBF) {
        ushort4 u; u.x = f2bf(o0); u.y = f2bf(o1); u.z = f2bf(o2); u.w = f2bf(o3);
        ((ushort4*)out)[(size_t)row * 256 + tid] = u;
    } else {
        float4 ov; ov.x = o0; ov.y = o1; ov.z = o2; ov.w = o3;
        ((float4*)out)[(size_t)row * 256 + tid] = ov;
    }
}

enum { E_BF16 = 0, E_BIAS_BF16, E_BIAS_GELU_BF16, E_BIAS_TPOS_F32, E_ADD_F32, E_BIAS_ADD_F32 };

// ---------------------------------------------------------------------------
// m97-structure GEMM + T2 swizzle: 128x128 tile, BK=64, 4 waves, 32 KB LDS
// (-> 3 blocks/CU), global_load_lds staging with pre-swizzled source,
// conflict-free swizzled ds_read_b128 (cp = c ^ (row&7)), XCD swizzle.
// C(M,N) = A(M,K) @ Bt(N,K)^T.
// ---------------------------------------------------------------------------
template<int EPI>
__global__ __launch_bounds__(256, 2)
void gemm_bt(const unsigned short* __restrict__ A, const unsigned short* __restrict__ Bt,
             void* __restrict__ Out,
             const float* __restrict__ bias, const float* __restrict__ addsrc,
             const float* __restrict__ tpos,
             int M, int N, int K)
{
    __shared__ unsigned short lds[2 * 128 * 64];
    const int tid  = threadIdx.x;
    const int wave = tid >> 6, lane = tid & 63;
    const int nbx  = N >> 7;

    // bijective XCD swizzle (grids here are multiples of 8)
    const int nwg = gridDim.x;
    int bid = blockIdx.x;
    int wg = ((nwg & 7) == 0) ? ((bid & 7) * (nwg >> 3) + (bid >> 3)) : bid;
    const int by = wg / nbx, bx = wg % nbx;

    // staging source: lane covers LDS slot (row = c*8 + (lane>>3), cp = lane&7);
    // pre-swizzle global k-chunk: logical = cp ^ (row&7) = (lane&7) ^ (lane>>3)
    const int swz = ((lane & 7) ^ (lane >> 3)) * 8;
    const unsigned short* gA = A  + (size_t)(by * 128 + (lane >> 3)) * K + swz;
    const unsigned short* gB = Bt + (size_t)(bx * 128 + (lane >> 3)) * K + swz;

    const int wr = wave >> 1, wc = wave & 1;
    f32x4 acc[4][4] = {};

    unsigned short* ldsA = lds;
    unsigned short* ldsB = lds + 128 * 64;

    // read-side swizzled chunk offsets (u16): chunk c = (lane>>4) + 4*kk, row&7 = lane&7
    const int off0 = (((lane >> 4)    ) ^ (lane & 7)) * 8;
    const int off1 = (((lane >> 4) | 4) ^ (lane & 7)) * 8;
    const unsigned short* la = ldsA + (wr * 64 + (lane & 15)) * 64;
    const unsigned short* lb = ldsB + (wc * 64 + (lane & 15)) * 64;

    for (int kt = 0; kt < K; kt += 64) {
#pragma unroll
        for (int j = 0; j < 4; ++j) {
            const int chunk = (j << 2) + wave;   // wave-uniform
            GLL16(gA + (size_t)chunk * 8 * K + kt, ldsA + chunk * 512);
            GLL16(gB + (size_t)chunk * 8 * K + kt, ldsB + chunk * 512);
        }
        __syncthreads();
#pragma unroll
        for (int kk = 0; kk < 2; ++kk) {
            const int offk = kk ? off1 : off0;
            bf16x8 a[4], b[4];
#pragma unroll
            for (int m = 0; m < 4; ++m) a[m] = *(const bf16x8*)(la + m * 1024 + offk);
#pragma unroll
            for (int n = 0; n < 4; ++n) b[n] = *(const bf16x8*)(lb + n * 1024 + offk);
#pragma unroll
            for (int m = 0; m < 4; ++m)
#pragma unroll
                for (int n = 0; n < 4; ++n)
                    acc[m][n] = __builtin_amdgcn_mfma_f32_16x16x32_bf16(a[m], b[n], acc[m][n], 0, 0, 0);
        }
        __syncthreads();
    }

    // epilogue: C/D layout col = lane&15, row = (lane>>4)*4 + reg
    const int r0 = by * 128 + wr * 64 + (lane >> 4) * 4;
    const int c0 = bx * 128 + wc * 64 + (lane & 15);
#pragma unroll
    for (int m = 0; m < 4; ++m) {
#pragma unroll
        for (int n = 0; n < 4; ++n) {
            const int c = c0 + n * 16;
#pragma unroll
            for (int j = 0; j < 4; ++j) {
                const int r = r0 + m * 16 + j;
                float v = acc[m][n][j];
                if (EPI == E_BIAS_BF16 || EPI == E_BIAS_GELU_BF16 ||
                    EPI == E_BIAS_TPOS_F32 || EPI == E_BIAS_ADD_F32)
                    v += bias[c];
                if (EPI == E_BIAS_GELU_BF16) v = gelu_exact(v);
                if (EPI == E_BIAS_TPOS_F32)  v += tpos[(((unsigned)r >> 8) & 15) * 1024 + c];
                if (EPI == E_ADD_F32 || EPI == E_BIAS_ADD_F32) v += addsrc[(size_t)r * N + c];
                if (EPI == E_BIAS_TPOS_F32 || EPI == E_ADD_F32 || EPI == E_BIAS_ADD_F32)
                    ((float*)Out)[(size_t)r * N + c] = v;
                else
                    ((unsigned short*)Out)[(size_t)r * N + c] = f2bf(v);
            }
        }
    }
}

// ---------------------------------------------------------------------------
// Latent-stack GEMM: 64x128 tile, BK=64, 4 waves (wave tile 32x64), 24 KB LDS
// (-> up to 6 blocks/CU), same m97 skeleton + swizzle. For M=2048 shapes the
// grid becomes 256-1024 blocks instead of 128 (occupancy fix).
// ---------------------------------------------------------------------------
template<int EPI>
__global__ __launch_bounds__(256, 4)
void gemm64(const unsigned short* __restrict__ A, const unsigned short* __restrict__ Bt,
            void* __restrict__ Out,
            const float* __restrict__ bias, const float* __restrict__ addsrc,
            int M, int N, int K)
{
    __shared__ unsigned short lds[64 * 64 + 128 * 64];   // A (8 KB) then B (16 KB)
    const int tid  = threadIdx.x;
    const int wave = tid >> 6, lane = tid & 63;
    const int nbx  = N >> 7;

    const int nwg = gridDim.x;
    int bid = blockIdx.x;
    int wg = ((nwg & 7) == 0) ? ((bid & 7) * (nwg >> 3) + (bid >> 3)) : bid;
    const int by = wg / nbx, bx = wg % nbx;

    const int swz = ((lane & 7) ^ (lane >> 3)) * 8;
    const unsigned short* gA = A  + (size_t)(by * 64  + (lane >> 3)) * K + swz;
    const unsigned short* gB = Bt + (size_t)(bx * 128 + (lane >> 3)) * K + swz;

    const int wr = wave >> 1, wc = wave & 1;
    f32x4 acc[2][4] = {};

    unsigned short* ldsA = lds;
    unsigned short* ldsB = lds + 64 * 64;

    const int off0 = (((lane >> 4)    ) ^ (lane & 7)) * 8;
    const int off1 = (((lane >> 4) | 4) ^ (lane & 7)) * 8;
    const unsigned short* la = ldsA + (wr * 32 + (lane & 15)) * 64;
    const unsigned short* lb = ldsB + (wc * 64 + (lane & 15)) * 64;

    for (int kt = 0; kt < K; kt += 64) {
        // A: 8 chunks (c = wave, 4+wave); B: 16 chunks (c = j*4+wave)
        GLL16(gA + (size_t)(wave)     * 8 * K + kt, ldsA + (wave)      * 512);
        GLL16(gA + (size_t)(4 + wave) * 8 * K + kt, ldsA + (4 + wave)  * 512);
#pragma unroll
        for (int j = 0; j < 4; ++j) {
            const int chunk = (j << 2) + wave;
            GLL16(gB + (size_t)chunk * 8 * K + kt, ldsB + chunk * 512);
        }
        __syncthreads();
#pragma unroll
        for (int kk = 0; kk < 2; ++kk) {
            const int offk = kk ? off1 : off0;
            bf16x8 a[2], b[4];
#pragma unroll
            for (int m = 0; m < 2; ++m) a[m] = *(const bf16x8*)(la + m * 1024 + offk);
#pragma unroll
            for (int n = 0; n < 4; ++n) b[n] = *(const bf16x8*)(lb + n * 1024 + offk);
#pragma unroll
            for (int m = 0; m < 2; ++m)
#pragma unroll
                for (int n = 0; n < 4; ++n)
                    acc[m][n] = __builtin_amdgcn_mfma_f32_16x16x32_bf16(a[m], b[n], acc[m][n], 0, 0, 0);
        }
        __syncthreads();
    }

    const int r0 = by * 64 + wr * 32 + (lane >> 4) * 4;
    const int c0 = bx * 128 + wc * 64 + (lane & 15);
#pragma unroll
    for (int m = 0; m < 2; ++m) {
#pragma unroll
        for (int n = 0; n < 4; ++n) {
            const int c = c0 + n * 16;
#pragma unroll
            for (int j = 0; j < 4; ++j) {
                const int r = r0 + m * 16 + j;
                float v = acc[m][n][j];
                if (EPI == E_BIAS_BF16 || EPI == E_BIAS_GELU_BF16 || EPI == E_BIAS_ADD_F32)
                    v += bias[c];
                if (EPI == E_BIAS_GELU_BF16) v = gelu_exact(v);
                if (EPI == E_ADD_F32 || EPI == E_BIAS_ADD_F32) v += addsrc[(size_t)r * N + c];
                if (EPI == E_ADD_F32 || EPI == E_BIAS_ADD_F32)
                    ((float*)Out)[(size_t)r * N + c] = v;
                else
                    ((unsigned short*)Out)[(size_t)r * N + c] = f2bf(v);
            }
        }
    }
}

// ---------------------------------------------------------------------------
// Attention: one block per (bt, head). Q=16, F=272, DH=64.
// ---------------------------------------------------------------------------
__global__ __launch_bounds__(256)
void attn_k(const unsigned short* __restrict__ qkvl, const unsigned short* __restrict__ kvm,
            unsigned short* __restrict__ o)
{
    __shared__ unsigned short kv[272 * 72];
    __shared__ float sim[16 * 273];
    __shared__ float qs[16 * 68];
    __shared__ float red[64];

    const int bt = blockIdx.x >> 4, h = blockIdx.x & 15;
    const int tid = threadIdx.x;
    const int lane = tid & 63, wave = tid >> 6;
    const int r = tid & 15, grp = tid >> 4;

    {
        const int qi = tid >> 4, d0 = (tid & 15) * 4;
        const unsigned short* src = qkvl + (size_t)(bt * 16 + qi) * 3072 + h * 64 + d0;
        qs[qi * 68 + d0 + 0] = bf2f(src[0]);
        qs[qi * 68 + d0 + 1] = bf2f(src[1]);
        qs[qi * 68 + d0 + 2] = bf2f(src[2]);
        qs[qi * 68 + d0 + 3] = bf2f(src[3]);
    }
#pragma unroll
    for (int i = 0; i < 9; ++i) {
        int idx = i * 256 + tid;
        if (idx < 2176) {
            int f = idx >> 3, cp = idx & 7;
            const unsigned short* src = (f < 256)
                ? kvm  + (size_t)(bt * 256 + f) * 2048 + h * 64 + cp * 8
                : qkvl + (size_t)(bt * 16 + (f - 256)) * 3072 + 1024 + h * 64 + cp * 8;
            *(short8*)&kv[f * 72 + cp * 8] = *(const short8*)src;
        }
    }
    __syncthreads();

    float p[17];
#pragma unroll
    for (int i = 0; i < 17; ++i) p[i] = 0.f;
#pragma unroll
    for (int d = 0; d < 64; d += 8) {
        float q8[8];
#pragma unroll
        for (int j = 0; j < 8; ++j) q8[j] = qs[r * 68 + d + j];
#pragma unroll
        for (int i = 0; i < 17; ++i) {
            short8 k8 = *(const short8*)&kv[(grp + i * 16) * 72 + d];
#pragma unroll
            for (int j = 0; j < 8; ++j) p[i] += q8[j] * bf2f((unsigned short)k8[j]);
        }
    }
    float mx = -3.0e38f;
#pragma unroll
    for (int i = 0; i < 17; ++i) mx = fmaxf(mx, p[i]);
    mx = fmaxf(mx, __shfl_xor(mx, 16));
    mx = fmaxf(mx, __shfl_xor(mx, 32));
    if (lane < 16) red[wave * 16 + lane] = mx;
    __syncthreads();
    const float rowmax = fmaxf(fmaxf(red[r], red[16 + r]), fmaxf(red[32 + r], red[48 + r]));

    float sm = 0.f;
#pragma unroll
    for (int i = 0; i < 17; ++i) { p[i] = __expf(p[i] - rowmax); sm += p[i]; }
    sm += __shfl_xor(sm, 16);
    sm += __shfl_xor(sm, 32);
#pragma unroll
    for (int i = 0; i < 17; ++i) sim[r * 273 + grp + i * 16] = p[i];
    __syncthreads();
    if (lane < 16) red[wave * 16 + lane] = sm;
#pragma unroll
    for (int i = 0; i < 9; ++i) {
        int idx = i * 256 + tid;
        if (idx < 2176) {
            int f = idx >> 3, cp = idx & 7;
            const unsigned short* src = (f < 256)
                ? kvm  + (size_t)(bt * 256 + f) * 2048 + 1024 + h * 64 + cp * 8
                : qkvl + (size_t)(bt * 16 + (f - 256)) * 3072 + 2048 + h * 64 + cp * 8;
            *(short8*)&kv[f * 72 + cp * 8] = *(const short8*)src;
        }
    }
    __syncthreads();
    const float inv = 1.0f / (red[r] + red[16 + r] + red[32 + r] + red[48 + r]);

    float o0 = 0.f, o1 = 0.f, o2 = 0.f, o3 = 0.f;
    for (int f = 0; f < 272; ++f) {
        float pv = sim[r * 273 + f];
        short4v v4 = *(const short4v*)&kv[f * 72 + grp * 4];
        o0 += pv * bf2f((unsigned short)v4[0]);
        o1 += pv * bf2f((unsigned short)v4[1]);
        o2 += pv * bf2f((unsigned short)v4[2]);
        o3 += pv * bf2f((unsigned short)v4[3]);
    }
    unsigned short* dst = o + (size_t)(bt * 16 + r) * 1024 + h * 64 + grp * 4;
    dst[0] = f2bf(o0 * inv);
    dst[1] = f2bf(o1 * inv);
    dst[2] = f2bf(o2 * inv);
    dst[3] = f2bf(o3 * inv);
}

// ---------------------------------------------------------------------------
extern "C" void kernel_launch(void* const* d_in, const int* in_sizes, int n_in,
                              void* d_out, int out_size, void* d_ws, size_t ws_size,
                              hipStream_t stream)
{
    const float* x_f      = (const float*)d_in[0];
    const float* goal_w1  = (const float*)d_in[1];
    const float* goal_b1  = (const float*)d_in[2];
    const float* goal_w2  = (const float*)d_in[3];
    const float* goal_b2  = (const float*)d_in[4];
    const float* latents  = (const float*)d_in[5];
    const float* tpos     = (const float*)d_in[6];
    const float* lnm_g    = (const float*)d_in[7];
    const float* lnm_b    = (const float*)d_in[8];
    const float* lnl_g    = (const float*)d_in[9];
    const float* lnl_b    = (const float*)d_in[10];
    const float* wq       = (const float*)d_in[11];
    const float* wk       = (const float*)d_in[12];
    const float* wv       = (const float*)d_in[13];
    const float* wo       = (const float*)d_in[14];
    const float* ffn_g    = (const float*)d_in[15];
    const float* ffn_b    = (const float*)d_in[16];
    const float* ffw1     = (const float*)d_in[17];
    const float* ffb1     = (const float*)d_in[18];
    const float* ffw2     = (const float*)d_in[19];
    const float* ffb2     = (const float*)d_in[20];
    const float* fin_g    = (const float*)d_in[21];
    const float* fin_b    = (const float*)d_in[22];

    char* ws = (char*)d_ws;
    size_t off = 0;
    auto alloc = [&](size_t bytes) -> char* {
        char* p = ws + off;
        off += (bytes + 255) & ~(size_t)255;
        return p;
    };
    typedef unsigned short u16;
    u16*   wg1t   = (u16*)  alloc(2048ull * 1280 * 2);
    u16*   wg2t   = (u16*)  alloc(1024ull * 2048 * 2);
    u16*   wqkvl  = (u16*)  alloc(6ull * 3072 * 1024 * 2);
    u16*   wkvm   = (u16*)  alloc(6ull * 2048 * 1024 * 2);
    u16*   wot    = (u16*)  alloc(6ull * 1024 * 1024 * 2);
    u16*   wf1t   = (u16*)  alloc(6ull * 4096 * 1024 * 2);
    u16*   wf2t   = (u16*)  alloc(6ull * 1024 * 4096 * 2);
    float* biaskv = (float*)alloc(6ull * 2048 * 4);
    float* xres   = (float*)alloc(2048ull * 1024 * 4);
    u16*   latn   = (u16*)  alloc(2048ull * 1024 * 2);
    u16*   qkvl   = (u16*)  alloc(2048ull * 3072 * 2);
    u16*   obuf   = (u16*)  alloc(2048ull * 1024 * 2);
    u16*   ffny   = (u16*)  alloc(2048ull * 1024 * 2);
    u16*   ffnmid = (u16*)  alloc(2048ull * 4096 * 2);
    u16*   bufA   = (u16*)  alloc(32768ull * 2048 * 2);
    float* bufB   = (float*)alloc(32768ull * 1024 * 4);
    u16*   bufC   = (u16*)  alloc(41943040ull * 2);
    if (off > ws_size) return;

    // ---- phase 0: conversions / folds ----
    convert_bf16<<<40960, 256, 0, stream>>>(x_f, bufC, 41943040ull / 4);
    transpose_w<<<dim3(32, 20, 1), 256, 0, stream>>>(goal_w1, wg1t, nullptr, 1.f, 1280, 2048, 0, 0, 0);
    transpose_w<<<dim3(16, 32, 1), 256, 0, stream>>>(goal_w2, wg2t, nullptr, 1.f, 2048, 1024, 0, 0, 0);
    transpose_w<<<dim3(16, 16, 6), 256, 0, stream>>>(wq, wqkvl,                nullptr, 0.125f, 1024, 1024, 1024ull*1024, 3072ull*1024, 0);
    transpose_w<<<dim3(16, 16, 6), 256, 0, stream>>>(wk, wqkvl + 1024ull*1024, nullptr, 1.f,    1024, 1024, 1024ull*1024, 3072ull*1024, 0);
    transpose_w<<<dim3(16, 16, 6), 256, 0, stream>>>(wv, wqkvl + 2048ull*1024, nullptr, 1.f,    1024, 1024, 1024ull*1024, 3072ull*1024, 0);
    transpose_w<<<dim3(16, 16, 6), 256, 0, stream>>>(wk, wkvm,                 lnm_g,   1.f,    1024, 1024, 1024ull*1024, 2048ull*1024, 1024);
    transpose_w<<<dim3(16, 16, 6), 256, 0, stream>>>(wv, wkvm + 1024ull*1024,  lnm_g,   1.f,    1024, 1024, 1024ull*1024, 2048ull*1024, 1024);
    transpose_w<<<dim3(16, 16, 6), 256, 0, stream>>>(wo, wot,                  nullptr, 1.f,    1024, 1024, 1024ull*1024, 1024ull*1024, 0);
    transpose_w<<<dim3(64, 16, 6), 256, 0, stream>>>(ffw1, wf1t,               nullptr, 1.f,    1024, 4096, 4096ull*1024, 4096ull*1024, 0);
    transpose_w<<<dim3(16, 64, 6), 256, 0, stream>>>(ffw2, wf2t,               nullptr, 1.f,    4096, 1024, 4096ull*1024, 4096ull*1024, 0);
    fold_bias<<<48, 256, 0, stream>>>(wk, wv, lnm_b, biaskv);
    init_x<<<2048, 256, 0, stream>>>(latents, xres);

    // ---- goal MLP ----
    gemm_bt<E_BIAS_GELU_BF16><<<256 * 16, 256, 0, stream>>>(bufC, wg1t, bufA, goal_b1, nullptr, nullptr, 32768, 2048, 1280);
    gemm_bt<E_BIAS_TPOS_F32><<<256 * 8, 256, 0, stream>>>(bufA, wg2t, bufB, goal_b2, nullptr, tpos, 32768, 1024, 2048);
    ln_k<false, true><<<32768, 256, 0, stream>>>(bufB, nullptr, nullptr, bufC);

    // ---- depth loop ----
    for (int i = 0; i < 6; ++i) {
        const u16* wqkvl_i = wqkvl + (size_t)i * 3072 * 1024;
        const u16* wkvm_i  = wkvm  + (size_t)i * 2048 * 1024;
        const u16* wot_i   = wot   + (size_t)i * 1024 * 1024;
        const u16* wf1_i   = wf1t  + (size_t)i * 4096 * 1024;
        const u16* wf2_i   = wf2t  + (size_t)i * 1024 * 4096;

        ln_k<true, true><<<2048, 256, 0, stream>>>(xres, lnl_g + i * 1024, lnl_b + i * 1024, latn);
        gemm64<E_BF16><<<32 * 24, 256, 0, stream>>>(latn, wqkvl_i, qkvl, nullptr, nullptr, 2048, 3072, 1024);
        gemm_bt<E_BIAS_BF16><<<256 * 16, 256, 0, stream>>>(bufC, wkvm_i, bufA, biaskv + i * 2048, nullptr, nullptr, 32768, 2048, 1024);
        attn_k<<<2048, 256, 0, stream>>>(qkvl, bufA, obuf);
        gemm64<E_ADD_F32><<<32 * 8, 256, 0, stream>>>(obuf, wot_i, xres, nullptr, xres, 2048, 1024, 1024);
        ln_k<true, true><<<2048, 256, 0, stream>>>(xres, ffn_g + i * 1024, ffn_b + i * 1024, ffny);
        gemm64<E_BIAS_GELU_BF16><<<32 * 32, 256, 0, stream>>>(ffny, wf1_i, ffnmid, ffb1 + i * 4096, nullptr, 2048, 4096, 1024);
        gemm64<E_BIAS_ADD_F32><<<32 * 8, 256, 0, stream>>>(ffnmid, wf2_i, xres, ffb2 + i * 1024, xres, 2048, 1024, 4096);
    }

    // ---- final LN -> d_out (f32) ----
    ln_k<true, false><<<2048, 256, 0, stream>>>(xres, fin_g, fin_b, d_out);
}

// Round 5
// 2770.940 us; speedup vs baseline: 1.2265x; 1.0194x over previous
//
#include <hip/hip_runtime.h>
#include <math.h>

#define DEV __device__ __forceinline__

typedef __attribute__((ext_vector_type(8))) short short8;
typedef __attribute__((ext_vector_type(4))) short short4v;
typedef __attribute__((ext_vector_type(4))) float f32x4;
typedef __attribute__((ext_vector_type(8))) __bf16 bf16x8;

DEV float bf2f(unsigned short u) {
    union { unsigned int i; float f; } c; c.i = ((unsigned int)u) << 16; return c.f;
}
DEV unsigned short f2bf(float f) {
    union { float f; unsigned int i; } c; c.f = f;
    unsigned int u = c.i;
    u += 0x7fffu + ((u >> 16) & 1u);   // RNE
    return (unsigned short)(u >> 16);
}
DEV float gelu_exact(float x) { return 0.5f * x * (1.0f + erff(x * 0.70710678118654752f)); }

DEV f32x4 MF(bf16x8 a, bf16x8 b, f32x4 c) {
    return __builtin_amdgcn_mfma_f32_16x16x32_bf16(a, b, c, 0, 0, 0);
}

#define GLL16(g, l)                                                                   \
    __builtin_amdgcn_global_load_lds(                                                \
        (const __attribute__((address_space(1))) unsigned int*)(g),                  \
        (__attribute__((address_space(3))) unsigned int*)(l), 16, 0, 0)

#define BAR()   __builtin_amdgcn_s_barrier()
#define LGKM0() asm volatile("s_waitcnt lgkmcnt(0)" ::: "memory")

// ---------------------------------------------------------------------------
// Weight transpose + f32->bf16 convert: in (K,N) f32 row-major -> out (N,K) bf16.
// ---------------------------------------------------------------------------
__global__ __launch_bounds__(256)
void transpose_w(const float* __restrict__ in, unsigned short* __restrict__ out,
                 const float* __restrict__ rowscale, float uscale,
                 int K, int N, size_t inStride, size_t outStride, int scaleStride)
{
    __shared__ float tile[64][65];
    in  += (size_t)blockIdx.z * inStride;
    out += (size_t)blockIdx.z * outStride;
    const int k0 = blockIdx.y * 64, n0 = blockIdx.x * 64;
    const int tid = threadIdx.x;
    const int c = tid & 63;
#pragma unroll
    for (int i = 0; i < 16; ++i) {
        int rr = (i << 2) + (tid >> 6);
        float v = in[(size_t)(k0 + rr) * N + n0 + c];
        if (rowscale) v *= rowscale[(size_t)blockIdx.z * scaleStride + k0 + rr];
        tile[rr][c] = v * uscale;
    }
    __syncthreads();
#pragma unroll
    for (int i = 0; i < 16; ++i) {
        int rr = (i << 2) + (tid >> 6);
        out[(size_t)(n0 + rr) * K + k0 + c] = f2bf(tile[c][rr]);
    }
}

// bias_kv[d][c] = sum_r ln_media_b[d][r] * w[d][r][c]
__global__ __launch_bounds__(256)
void fold_bias(const float* __restrict__ wk, const float* __restrict__ wv,
               const float* __restrict__ bmed, float* __restrict__ biaskv)
{
    const int d = blockIdx.x >> 3;
    const int rem = blockIdx.x & 7;
    const int part = rem >> 2;
    const int chunk = rem & 3;
    const float* w = (part ? wv : wk) + (size_t)d * 1024 * 1024 + chunk * 256 + threadIdx.x;
    const float* b = bmed + d * 1024;
    float acc = 0.f;
    for (int r = 0; r < 1024; ++r) acc += b[r] * w[(size_t)r * 1024];
    biaskv[d * 2048 + part * 1024 + chunk * 256 + threadIdx.x] = acc;
}

__global__ __launch_bounds__(256)
void convert_bf16(const float* __restrict__ in, unsigned short* __restrict__ out, size_t n4)
{
    size_t i = (size_t)blockIdx.x * 256 + threadIdx.x;
    if (i >= n4) return;
    float4 v = ((const float4*)in)[i];
    ushort4 u;
    u.x = f2bf(v.x); u.y = f2bf(v.y); u.z = f2bf(v.z); u.w = f2bf(v.w);
    ((ushort4*)out)[i] = u;
}

__global__ __launch_bounds__(256)
void init_x(const float* __restrict__ lat, float* __restrict__ x)
{
    const int row = blockIdx.x;
    ((float4*)x)[(size_t)row * 256 + threadIdx.x] =
        ((const float4*)lat)[(size_t)(row & 255) * 256 + threadIdx.x];
}

// ---------------------------------------------------------------------------
// LayerNorm over D=1024, one row per block.
// ---------------------------------------------------------------------------
template<bool AFFINE, bool OUTBF>
__global__ __launch_bounds__(256)
void ln_k(const float* __restrict__ in, const float* __restrict__ g,
          const float* __restrict__ b, void* __restrict__ out)
{
    const int row = blockIdx.x;
    const int tid = threadIdx.x;
    float4 v = ((const float4*)(in + (size_t)row * 1024))[tid];
    float s  = v.x + v.y + v.z + v.w;
    float ss = v.x * v.x + v.y * v.y + v.z * v.z + v.w * v.w;
#pragma unroll
    for (int o = 32; o > 0; o >>= 1) { s += __shfl_down(s, o); ss += __shfl_down(ss, o); }
    __shared__ float red[8];
    if ((tid & 63) == 0) { red[tid >> 6] = s; red[4 + (tid >> 6)] = ss; }
    __syncthreads();
    const float sum  = red[0] + red[1] + red[2] + red[3];
    const float ssum = red[4] + red[5] + red[6] + red[7];
    const float mean = sum * (1.0f / 1024.0f);
    const float var  = ssum * (1.0f / 1024.0f) - mean * mean;
    const float rs   = rsqrtf(var + 1e-5f);
    float o0 = (v.x - mean) * rs, o1 = (v.y - mean) * rs;
    float o2 = (v.z - mean) * rs, o3 = (v.w - mean) * rs;
    if (AFFINE) {
        float4 gv = ((const float4*)g)[tid];
        float4 bv = ((const float4*)b)[tid];
        o0 = o0 * gv.x + bv.x; o1 = o1 * gv.y + bv.y;
        o2 = o2 * gv.z + bv.z; o3 = o3 * gv.w + bv.w;
    }
    if (OUTBF) {
        ushort4 u; u.x = f2bf(o0); u.y = f2bf(o1); u.z = f2bf(o2); u.w = f2bf(o3);
        ((ushort4*)out)[(size_t)row * 256 + tid] = u;
    } else {
        float4 ov; ov.x = o0; ov.y = o1; ov.z = o2; ov.w = o3;
        ((float4*)out)[(size_t)row * 256 + tid] = ov;
    }
}

enum { E_BF16 = 0, E_BIAS_BF16, E_BIAS_GELU_BF16, E_BIAS_TPOS_F32, E_ADD_F32, E_BIAS_ADD_F32 };

// ---------------------------------------------------------------------------
// Big-shape GEMM: m201-style 256x256 8-phase template.
// 8 waves (2Mx4N), BK=64, LDS = 2dbuf x 2half x 128rows x 64k x {A,B} = 128 KiB.
// Per K-tile: 4 phases, each = {ds_read quadrant subtile, stage half-tile,
// barrier, lgkmcnt(0), setprio(1), 16 MFMA (one C-quadrant x K=64), setprio(0),
// barrier}. Counted vmcnt(4) once per K-tile (never 0 mid-loop).
// A-half h = rows with mi in [4h,4h+4) (read only in phases 2h,2h+1);
// B read entirely in phase 0 -> every staged region is dead >=1 barrier before
// overwrite (race-free by construction).
// Zero-conflict 8-chunk XOR swizzle on staging source + reads (r4-verified).
// C(M,N) = A(M,K) @ Bt(N,K)^T. Requires M%256==0, N%256==0, K%64==0, grid%8==0.
// ---------------------------------------------------------------------------
template<int EPI>
__global__ __launch_bounds__(512, 2)
void g8p(const unsigned short* __restrict__ A, const unsigned short* __restrict__ Bt,
         void* __restrict__ Out,
         const float* __restrict__ bias, const float* __restrict__ tpos,
         int M, int N, int K)
{
    // layout (u16): A d=0 halves @0,8192; A d=1 @16384,24576; B d=0 @32768,40960; B d=1 @49152,57344
    __shared__ unsigned short sm[65536];

    const int tid = threadIdx.x;
    const int wid = tid >> 6, lane = tid & 63;
    const int wm = wid >> 2, wn = wid & 3;

    const int nbx = N >> 8;
    const int nwg = gridDim.x;
    const int bid = blockIdx.x;
    const int wg = (bid & 7) * (nwg >> 3) + (bid >> 3);   // bijective, nwg%8==0
    const int by = wg / nbx, bx = wg % nbx;
    const int nt = K >> 6;

    // staging: thread covers (row srow, physical chunk lane&7); logical chunk pre-swizzled
    const int srow = wid * 8 + (lane >> 3);               // 0..63
    const int schk = ((lane & 7) ^ (lane >> 3)) * 8;
    const unsigned short* gA = A  + (size_t)(by * 256 + srow) * K + schk;
    const unsigned short* gB = Bt + (size_t)(bx * 256 + srow) * K + schk;
    const int ldst = wid * 512;                           // wave-uniform LDS dest (u16)

    // stgA half h: global tile rows = srow + h*64 (+128 for j=1)  [A-half h = mi in 4h..4h+3]
    auto stgA = [&](int d, int h, int T) {
        const unsigned short* g = gA + (size_t)(h * 64) * K + (size_t)T * 64;
        unsigned short* l = sm + d * 16384 + h * 8192 + ldst;
        GLL16(g, l);
        GLL16(g + (size_t)128 * K, l + 4096);
    };
    // stgB half h: global rows = srow + h*128 (+64 for j=1)
    auto stgB = [&](int d, int h, int T) {
        const unsigned short* g = gB + (size_t)(h * 128) * K + (size_t)T * 64;
        unsigned short* l = sm + 32768 + d * 16384 + h * 8192 + ldst;
        GLL16(g, l);
        GLL16(g + (size_t)64 * K, l + 4096);
    };

    // fragment-read offsets (u16)
    const int q = lane >> 4;
    const int cks0 = ((q    ) ^ (lane & 7)) * 8;
    const int cks1 = ((q + 4) ^ (lane & 7)) * 8;
    const int arow = (wm * 64 + (lane & 15)) * 64;        // + (mi&3)*1024 within half
    const int brow = ((wn & 1) * 64 + (lane & 15)) * 64;  // + ni*1024 within half
    const int bhoff = 32768 + (wn >> 1) * 8192;

    f32x4 acc[8][4] = {};
    bf16x8 a[2][2], b[4][2];

    // ---- prologue: tile 0 complete + {B0,A0}(1) in flight ----
    stgA(0, 0, 0); stgA(0, 1, 0); stgB(0, 0, 0); stgB(0, 1, 0);
    if (nt > 1) { stgB(1, 0, 1); stgA(1, 0, 1); }
    if (nt > 1) asm volatile("s_waitcnt vmcnt(4)" ::: "memory");
    else        asm volatile("s_waitcnt vmcnt(0)" ::: "memory");
    BAR();

#define PH_READ_A(HOFF, E0)                                                      \
    a[0][0] = *(const bf16x8*)(Ab + (HOFF) + arow + (E0) * 1024 + cks0);         \
    a[0][1] = *(const bf16x8*)(Ab + (HOFF) + arow + (E0) * 1024 + cks1);         \
    a[1][0] = *(const bf16x8*)(Ab + (HOFF) + arow + ((E0) + 1) * 1024 + cks0);   \
    a[1][1] = *(const bf16x8*)(Ab + (HOFF) + arow + ((E0) + 1) * 1024 + cks1);

#define PH_MFMA(R0)                                                              \
    __builtin_amdgcn_s_setprio(1);                                               \
    _Pragma("unroll")                                                            \
    for (int e = 0; e < 2; ++e)                                                  \
        _Pragma("unroll")                                                        \
        for (int ni = 0; ni < 4; ++ni) {                                         \
            acc[(R0) + e][ni] = MF(a[e][0], b[ni][0], acc[(R0) + e][ni]);        \
            acc[(R0) + e][ni] = MF(a[e][1], b[ni][1], acc[(R0) + e][ni]);        \
        }                                                                        \
    __builtin_amdgcn_s_setprio(0);

    for (int T = 0; T < nt; ++T) {
        const int d = T & 1, dn = d ^ 1;
        const unsigned short* Ab = sm + d * 16384;
        const unsigned short* Bb = sm + bhoff + d * 16384;
        const bool s1 = (T + 1 < nt), s2 = (T + 2 < nt);

        // -------- phase 0: Q0 (mi 0,1) + full b-load (12 ds_reads) --------
        PH_READ_A(0, 0);
#pragma unroll
        for (int ni = 0; ni < 4; ++ni) {
            b[ni][0] = *(const bf16x8*)(Bb + brow + ni * 1024 + cks0);
            b[ni][1] = *(const bf16x8*)(Bb + brow + ni * 1024 + cks1);
        }
        if (s1) { stgB(dn, 1, T + 1); stgA(dn, 1, T + 1); }
        BAR(); LGKM0();
        PH_MFMA(0);
        BAR();

        // -------- phase 1: Q1 (mi 2,3) --------
        PH_READ_A(0, 2);
        if (s2) stgB(d, 0, T + 2);
        BAR(); LGKM0();
        PH_MFMA(2);
        BAR();

        // -------- phase 2: Q2 (mi 4,5) --------
        PH_READ_A(8192, 0);
        if (s2) stgA(d, 0, T + 2);
        BAR(); LGKM0();
        PH_MFMA(4);
        BAR();

        // -------- phase 3: Q3 (mi 6,7) + tile-boundary vmcnt --------
        PH_READ_A(8192, 2);
        BAR(); LGKM0();
        PH_MFMA(6);
        if (s2)      asm volatile("s_waitcnt vmcnt(4)" ::: "memory");
        else if (s1) asm volatile("s_waitcnt vmcnt(0)" ::: "memory");
        BAR();
    }
#undef PH_READ_A
#undef PH_MFMA

    // -------- epilogue: C/D layout col = lane&15, row = (lane>>4)*4 + reg --------
    const int r0 = by * 256 + wm * 128 + (lane >> 4) * 4;
    const int c0 = bx * 256 + wn * 64 + (lane & 15);
#pragma unroll
    for (int mi = 0; mi < 8; ++mi) {
#pragma unroll
        for (int ni = 0; ni < 4; ++ni) {
            const int c = c0 + ni * 16;
            float bv = 0.f;
            if (EPI == E_BIAS_BF16 || EPI == E_BIAS_GELU_BF16 || EPI == E_BIAS_TPOS_F32)
                bv = bias[c];
#pragma unroll
            for (int j = 0; j < 4; ++j) {
                const int r = r0 + mi * 16 + j;
                float v = acc[mi][ni][j] + bv;
                if (EPI == E_BIAS_GELU_BF16) v = gelu_exact(v);
                if (EPI == E_BIAS_TPOS_F32) {
                    v += tpos[(((unsigned)r >> 8) & 15) * 1024 + c];
                    ((float*)Out)[(size_t)r * N + c] = v;
                } else {
                    ((unsigned short*)Out)[(size_t)r * N + c] = f2bf(v);
                }
            }
        }
    }
}

// ---------------------------------------------------------------------------
// Latent-stack GEMM: 64x128 tile, BK=64, 4 waves, 24 KB LDS, m97 skeleton +
// zero-conflict swizzle (r4-verified).
// ---------------------------------------------------------------------------
template<int EPI>
__global__ __launch_bounds__(256, 4)
void gemm64(const unsigned short* __restrict__ A, const unsigned short* __restrict__ Bt,
            void* __restrict__ Out,
            const float* __restrict__ bias, const float* __restrict__ addsrc,
            int M, int N, int K)
{
    __shared__ unsigned short lds[64 * 64 + 128 * 64];
    const int tid  = threadIdx.x;
    const int wave = tid >> 6, lane = tid & 63;
    const int nbx  = N >> 7;

    const int nwg = gridDim.x;
    int bid = blockIdx.x;
    int wg = ((nwg & 7) == 0) ? ((bid & 7) * (nwg >> 3) + (bid >> 3)) : bid;
    const int by = wg / nbx, bx = wg % nbx;

    const int swz = ((lane & 7) ^ (lane >> 3)) * 8;
    const unsigned short* gA = A  + (size_t)(by * 64  + (lane >> 3)) * K + swz;
    const unsigned short* gB = Bt + (size_t)(bx * 128 + (lane >> 3)) * K + swz;

    const int wr = wave >> 1, wc = wave & 1;
    f32x4 acc[2][4] = {};

    unsigned short* ldsA = lds;
    unsigned short* ldsB = lds + 64 * 64;

    const int off0 = (((lane >> 4)    ) ^ (lane & 7)) * 8;
    const int off1 = (((lane >> 4) | 4) ^ (lane & 7)) * 8;
    const unsigned short* la = ldsA + (wr * 32 + (lane & 15)) * 64;
    const unsigned short* lb = ldsB + (wc * 64 + (lane & 15)) * 64;

    for (int kt = 0; kt < K; kt += 64) {
        GLL16(gA + (size_t)(wave)     * 8 * K + kt, ldsA + (wave)      * 512);
        GLL16(gA + (size_t)(4 + wave) * 8 * K + kt, ldsA + (4 + wave)  * 512);
#pragma unroll
        for (int j = 0; j < 4; ++j) {
            const int chunk = (j << 2) + wave;
            GLL16(gB + (size_t)chunk * 8 * K + kt, ldsB + chunk * 512);
        }
        __syncthreads();
#pragma unroll
        for (int kk = 0; kk < 2; ++kk) {
            const int offk = kk ? off1 : off0;
            bf16x8 a[2], b[4];
#pragma unroll
            for (int m = 0; m < 2; ++m) a[m] = *(const bf16x8*)(la + m * 1024 + offk);
#pragma unroll
            for (int n = 0; n < 4; ++n) b[n] = *(const bf16x8*)(lb + n * 1024 + offk);
#pragma unroll
            for (int m = 0; m < 2; ++m)
#pragma unroll
                for (int n = 0; n < 4; ++n)
                    acc[m][n] = __builtin_amdgcn_mfma_f32_16x16x32_bf16(a[m], b[n], acc[m][n], 0, 0, 0);
        }
        __syncthreads();
    }

    const int r0 = by * 64 + wr * 32 + (lane >> 4) * 4;
    const int c0 = bx * 128 + wc * 64 + (lane & 15);
#pragma unroll
    for (int m = 0; m < 2; ++m) {
#pragma unroll
        for (int n = 0; n < 4; ++n) {
            const int c = c0 + n * 16;
#pragma unroll
            for (int j = 0; j < 4; ++j) {
                const int r = r0 + m * 16 + j;
                float v = acc[m][n][j];
                if (EPI == E_BIAS_BF16 || EPI == E_BIAS_GELU_BF16 || EPI == E_BIAS_ADD_F32)
                    v += bias[c];
                if (EPI == E_BIAS_GELU_BF16) v = gelu_exact(v);
                if (EPI == E_ADD_F32 || EPI == E_BIAS_ADD_F32) v += addsrc[(size_t)r * N + c];
                if (EPI == E_ADD_F32 || EPI == E_BIAS_ADD_F32)
                    ((float*)Out)[(size_t)r * N + c] = v;
                else
                    ((unsigned short*)Out)[(size_t)r * N + c] = f2bf(v);
            }
        }
    }
}

// ---------------------------------------------------------------------------
// Attention: one block per (bt, head). Q=16, F=272, DH=64.
// ---------------------------------------------------------------------------
__global__ __launch_bounds__(256)
void attn_k(const unsigned short* __restrict__ qkvl, const unsigned short* __restrict__ kvm,
            unsigned short* __restrict__ o)
{
    __shared__ unsigned short kv[272 * 72];
    __shared__ float sim[16 * 273];
    __shared__ float qs[16 * 68];
    __shared__ float red[64];

    const int bt = blockIdx.x >> 4, h = blockIdx.x & 15;
    const int tid = threadIdx.x;
    const int lane = tid & 63, wave = tid >> 6;
    const int r = tid & 15, grp = tid >> 4;

    {
        const int qi = tid >> 4, d0 = (tid & 15) * 4;
        const unsigned short* src = qkvl + (size_t)(bt * 16 + qi) * 3072 + h * 64 + d0;
        qs[qi * 68 + d0 + 0] = bf2f(src[0]);
        qs[qi * 68 + d0 + 1] = bf2f(src[1]);
        qs[qi * 68 + d0 + 2] = bf2f(src[2]);
        qs[qi * 68 + d0 + 3] = bf2f(src[3]);
    }
#pragma unroll
    for (int i = 0; i < 9; ++i) {
        int idx = i * 256 + tid;
        if (idx < 2176) {
            int f = idx >> 3, cp = idx & 7;
            const unsigned short* src = (f < 256)
                ? kvm  + (size_t)(bt * 256 + f) * 2048 + h * 64 + cp * 8
                : qkvl + (size_t)(bt * 16 + (f - 256)) * 3072 + 1024 + h * 64 + cp * 8;
            *(short8*)&kv[f * 72 + cp * 8] = *(const short8*)src;
        }
    }
    __syncthreads();

    float p[17];
#pragma unroll
    for (int i = 0; i < 17; ++i) p[i] = 0.f;
#pragma unroll
    for (int d = 0; d < 64; d += 8) {
        float q8[8];
#pragma unroll
        for (int j = 0; j < 8; ++j) q8[j] = qs[r * 68 + d + j];
#pragma unroll
        for (int i = 0; i < 17; ++i) {
            short8 k8 = *(const short8*)&kv[(grp + i * 16) * 72 + d];
#pragma unroll
            for (int j = 0; j < 8; ++j) p[i] += q8[j] * bf2f((unsigned short)k8[j]);
        }
    }
    float mx = -3.0e38f;
#pragma unroll
    for (int i = 0; i < 17; ++i) mx = fmaxf(mx, p[i]);
    mx = fmaxf(mx, __shfl_xor(mx, 16));
    mx = fmaxf(mx, __shfl_xor(mx, 32));
    if (lane < 16) red[wave * 16 + lane] = mx;
    __syncthreads();
    const float rowmax = fmaxf(fmaxf(red[r], red[16 + r]), fmaxf(red[32 + r], red[48 + r]));

    float sm = 0.f;
#pragma unroll
    for (int i = 0; i < 17; ++i) { p[i] = __expf(p[i] - rowmax); sm += p[i]; }
    sm += __shfl_xor(sm, 16);
    sm += __shfl_xor(sm, 32);
#pragma unroll
    for (int i = 0; i < 17; ++i) sim[r * 273 + grp + i * 16] = p[i];
    __syncthreads();
    if (lane < 16) red[wave * 16 + lane] = sm;
#pragma unroll
    for (int i = 0; i < 9; ++i) {
        int idx = i * 256 + tid;
        if (idx < 2176) {
            int f = idx >> 3, cp = idx & 7;
            const unsigned short* src = (f < 256)
                ? kvm  + (size_t)(bt * 256 + f) * 2048 + 1024 + h * 64 + cp * 8
                : qkvl + (size_t)(bt * 16 + (f - 256)) * 3072 + 2048 + h * 64 + cp * 8;
            *(short8*)&kv[f * 72 + cp * 8] = *(const short8*)src;
        }
    }
    __syncthreads();
    const float inv = 1.0f / (red[r] + red[16 + r] + red[32 + r] + red[48 + r]);

    float o0 = 0.f, o1 = 0.f, o2 = 0.f, o3 = 0.f;
    for (int f = 0; f < 272; ++f) {
        float pv = sim[r * 273 + f];
        short4v v4 = *(const short4v*)&kv[f * 72 + grp * 4];
        o0 += pv * bf2f((unsigned short)v4[0]);
        o1 += pv * bf2f((unsigned short)v4[1]);
        o2 += pv * bf2f((unsigned short)v4[2]);
        o3 += pv * bf2f((unsigned short)v4[3]);
    }
    unsigned short* dst = o + (size_t)(bt * 16 + r) * 1024 + h * 64 + grp * 4;
    dst[0] = f2bf(o0 * inv);
    dst[1] = f2bf(o1 * inv);
    dst[2] = f2bf(o2 * inv);
    dst[3] = f2bf(o3 * inv);
}

// ---------------------------------------------------------------------------
extern "C" void kernel_launch(void* const* d_in, const int* in_sizes, int n_in,
                              void* d_out, int out_size, void* d_ws, size_t ws_size,
                              hipStream_t stream)
{
    const float* x_f      = (const float*)d_in[0];
    const float* goal_w1  = (const float*)d_in[1];
    const float* goal_b1  = (const float*)d_in[2];
    const float* goal_w2  = (const float*)d_in[3];
    const float* goal_b2  = (const float*)d_in[4];
    const float* latents  = (const float*)d_in[5];
    const float* tpos     = (const float*)d_in[6];
    const float* lnm_g    = (const float*)d_in[7];
    const float* lnm_b    = (const float*)d_in[8];
    const float* lnl_g    = (const float*)d_in[9];
    const float* lnl_b    = (const float*)d_in[10];
    const float* wq       = (const float*)d_in[11];
    const float* wk       = (const float*)d_in[12];
    const float* wv       = (const float*)d_in[13];
    const float* wo       = (const float*)d_in[14];
    const float* ffn_g    = (const float*)d_in[15];
    const float* ffn_b    = (const float*)d_in[16];
    const float* ffw1     = (const float*)d_in[17];
    const float* ffb1     = (const float*)d_in[18];
    const float* ffw2     = (const float*)d_in[19];
    const float* ffb2     = (const float*)d_in[20];
    const float* fin_g    = (const float*)d_in[21];
    const float* fin_b    = (const float*)d_in[22];

    char* ws = (char*)d_ws;
    size_t off = 0;
    auto alloc = [&](size_t bytes) -> char* {
        char* p = ws + off;
        off += (bytes + 255) & ~(size_t)255;
        return p;
    };
    typedef unsigned short u16;
    u16*   wg1t   = (u16*)  alloc(2048ull * 1280 * 2);
    u16*   wg2t   = (u16*)  alloc(1024ull * 2048 * 2);
    u16*   wqkvl  = (u16*)  alloc(6ull * 3072 * 1024 * 2);
    u16*   wkvm   = (u16*)  alloc(6ull * 2048 * 1024 * 2);
    u16*   wot    = (u16*)  alloc(6ull * 1024 * 1024 * 2);
    u16*   wf1t   = (u16*)  alloc(6ull * 4096 * 1024 * 2);
    u16*   wf2t   = (u16*)  alloc(6ull * 1024 * 4096 * 2);
    float* biaskv = (float*)alloc(6ull * 2048 * 4);
    float* xres   = (float*)alloc(2048ull * 1024 * 4);
    u16*   latn   = (u16*)  alloc(2048ull * 1024 * 2);
    u16*   qkvl   = (u16*)  alloc(2048ull * 3072 * 2);
    u16*   obuf   = (u16*)  alloc(2048ull * 1024 * 2);
    u16*   ffny   = (u16*)  alloc(2048ull * 1024 * 2);
    u16*   ffnmid = (u16*)  alloc(2048ull * 4096 * 2);
    u16*   bufA   = (u16*)  alloc(32768ull * 2048 * 2);
    float* bufB   = (float*)alloc(32768ull * 1024 * 4);
    u16*   bufC   = (u16*)  alloc(41943040ull * 2);
    if (off > ws_size) return;

    // ---- phase 0: conversions / folds ----
    convert_bf16<<<40960, 256, 0, stream>>>(x_f, bufC, 41943040ull / 4);
    transpose_w<<<dim3(32, 20, 1), 256, 0, stream>>>(goal_w1, wg1t, nullptr, 1.f, 1280, 2048, 0, 0, 0);
    transpose_w<<<dim3(16, 32, 1), 256, 0, stream>>>(goal_w2, wg2t, nullptr, 1.f, 2048, 1024, 0, 0, 0);
    transpose_w<<<dim3(16, 16, 6), 256, 0, stream>>>(wq, wqkvl,                nullptr, 0.125f, 1024, 1024, 1024ull*1024, 3072ull*1024, 0);
    transpose_w<<<dim3(16, 16, 6), 256, 0, stream>>>(wk, wqkvl + 1024ull*1024, nullptr, 1.f,    1024, 1024, 1024ull*1024, 3072ull*1024, 0);
    transpose_w<<<dim3(16, 16, 6), 256, 0, stream>>>(wv, wqkvl + 2048ull*1024, nullptr, 1.f,    1024, 1024, 1024ull*1024, 3072ull*1024, 0);
    transpose_w<<<dim3(16, 16, 6), 256, 0, stream>>>(wk, wkvm,                 lnm_g,   1.f,    1024, 1024, 1024ull*1024, 2048ull*1024, 1024);
    transpose_w<<<dim3(16, 16, 6), 256, 0, stream>>>(wv, wkvm + 1024ull*1024,  lnm_g,   1.f,    1024, 1024, 1024ull*1024, 2048ull*1024, 1024);
    transpose_w<<<dim3(16, 16, 6), 256, 0, stream>>>(wo, wot,                  nullptr, 1.f,    1024, 1024, 1024ull*1024, 1024ull*1024, 0);
    transpose_w<<<dim3(64, 16, 6), 256, 0, stream>>>(ffw1, wf1t,               nullptr, 1.f,    1024, 4096, 4096ull*1024, 4096ull*1024, 0);
    transpose_w<<<dim3(16, 64, 6), 256, 0, stream>>>(ffw2, wf2t,               nullptr, 1.f,    4096, 1024, 4096ull*1024, 4096ull*1024, 0);
    fold_bias<<<48, 256, 0, stream>>>(wk, wv, lnm_b, biaskv);
    init_x<<<2048, 256, 0, stream>>>(latents, xres);

    // ---- goal MLP (8-phase 256^2) ----
    g8p<E_BIAS_GELU_BF16><<<1024, 512, 0, stream>>>(bufC, wg1t, bufA, goal_b1, nullptr, 32768, 2048, 1280);
    g8p<E_BIAS_TPOS_F32><<<512, 512, 0, stream>>>(bufA, wg2t, bufB, goal_b2, tpos, 32768, 1024, 2048);
    ln_k<false, true><<<32768, 256, 0, stream>>>(bufB, nullptr, nullptr, bufC);

    // ---- depth loop ----
    for (int i = 0; i < 6; ++i) {
        const u16* wqkvl_i = wqkvl + (size_t)i * 3072 * 1024;
        const u16* wkvm_i  = wkvm  + (size_t)i * 2048 * 1024;
        const u16* wot_i   = wot   + (size_t)i * 1024 * 1024;
        const u16* wf1_i   = wf1t  + (size_t)i * 4096 * 1024;
        const u16* wf2_i   = wf2t  + (size_t)i * 1024 * 4096;

        ln_k<true, true><<<2048, 256, 0, stream>>>(xres, lnl_g + i * 1024, lnl_b + i * 1024, latn);
        gemm64<E_BF16><<<32 * 24, 256, 0, stream>>>(latn, wqkvl_i, qkvl, nullptr, nullptr, 2048, 3072, 1024);
        g8p<E_BIAS_BF16><<<1024, 512, 0, stream>>>(bufC, wkvm_i, bufA, biaskv + i * 2048, nullptr, 32768, 2048, 1024);
        attn_k<<<2048, 256, 0, stream>>>(qkvl, bufA, obuf);
        gemm64<E_ADD_F32><<<32 * 8, 256, 0, stream>>>(obuf, wot_i, xres, nullptr, xres, 2048, 1024, 1024);
        ln_k<true, true><<<2048, 256, 0, stream>>>(xres, ffn_g + i * 1024, ffn_b + i * 1024, ffny);
        gemm64<E_BIAS_GELU_BF16><<<32 * 32, 256, 0, stream>>>(ffny, wf1_i, ffnmid, ffb1 + i * 4096, nullptr, 2048, 4096, 1024);
        gemm64<E_BIAS_ADD_F32><<<32 * 8, 256, 0, stream>>>(ffnmid, wf2_i, xres, ffb2 + i * 1024, xres, 2048, 1024, 4096);
    }

    // ---- final LN -> d_out (f32) ----
    ln_k<true, false><<<2048, 256, 0, stream>>>(xres, fin_g, fin_b, d_out);
}

// Round 6
// 2727.377 us; speedup vs baseline: 1.2461x; 1.0160x over previous
//
#include <hip/hip_runtime.h>
#include <math.h>

#define DEV __device__ __forceinline__

typedef __attribute__((ext_vector_type(8))) short short8;
typedef __attribute__((ext_vector_type(4))) short short4v;
typedef __attribute__((ext_vector_type(4))) float f32x4;
typedef __attribute__((ext_vector_type(8))) __bf16 bf16x8;

DEV float bf2f(unsigned short u) {
    union { unsigned int i; float f; } c; c.i = ((unsigned int)u) << 16; return c.f;
}
DEV unsigned short f2bf(float f) {
    union { float f; unsigned int i; } c; c.f = f;
    unsigned int u = c.i;
    u += 0x7fffu + ((u >> 16) & 1u);   // RNE
    return (unsigned short)(u >> 16);
}
DEV float gelu_exact(float x) { return 0.5f * x * (1.0f + erff(x * 0.70710678118654752f)); }

DEV f32x4 MF(bf16x8 a, bf16x8 b, f32x4 c) {
    return __builtin_amdgcn_mfma_f32_16x16x32_bf16(a, b, c, 0, 0, 0);
}

#define GLL16(g, l)                                                                   \
    __builtin_amdgcn_global_load_lds(                                                \
        (const __attribute__((address_space(1))) unsigned int*)(g),                  \
        (__attribute__((address_space(3))) unsigned int*)(l), 16, 0, 0)

#define BAR()     __builtin_amdgcn_s_barrier()
#define VMCNT(n)  asm volatile("s_waitcnt vmcnt(" #n ")" ::: "memory")
#define LGKM(n)   do { asm volatile("s_waitcnt lgkmcnt(" #n ")" ::: "memory");        \
                       __builtin_amdgcn_sched_barrier(0); } while (0)

// ---------------------------------------------------------------------------
// Weight transpose + f32->bf16 convert: in (K,N) f32 row-major -> out (N,K) bf16.
// ---------------------------------------------------------------------------
__global__ __launch_bounds__(256)
void transpose_w(const float* __restrict__ in, unsigned short* __restrict__ out,
                 const float* __restrict__ rowscale, float uscale,
                 int K, int N, size_t inStride, size_t outStride, int scaleStride)
{
    __shared__ float tile[64][65];
    in  += (size_t)blockIdx.z * inStride;
    out += (size_t)blockIdx.z * outStride;
    const int k0 = blockIdx.y * 64, n0 = blockIdx.x * 64;
    const int tid = threadIdx.x;
    const int c = tid & 63;
#pragma unroll
    for (int i = 0; i < 16; ++i) {
        int rr = (i << 2) + (tid >> 6);
        float v = in[(size_t)(k0 + rr) * N + n0 + c];
        if (rowscale) v *= rowscale[(size_t)blockIdx.z * scaleStride + k0 + rr];
        tile[rr][c] = v * uscale;
    }
    __syncthreads();
#pragma unroll
    for (int i = 0; i < 16; ++i) {
        int rr = (i << 2) + (tid >> 6);
        out[(size_t)(n0 + rr) * K + k0 + c] = f2bf(tile[c][rr]);
    }
}

// bias_kv[d][c] = sum_r ln_media_b[d][r] * w[d][r][c]
__global__ __launch_bounds__(256)
void fold_bias(const float* __restrict__ wk, const float* __restrict__ wv,
               const float* __restrict__ bmed, float* __restrict__ biaskv)
{
    const int d = blockIdx.x >> 3;
    const int rem = blockIdx.x & 7;
    const int part = rem >> 2;
    const int chunk = rem & 3;
    const float* w = (part ? wv : wk) + (size_t)d * 1024 * 1024 + chunk * 256 + threadIdx.x;
    const float* b = bmed + d * 1024;
    float acc = 0.f;
    for (int r = 0; r < 1024; ++r) acc += b[r] * w[(size_t)r * 1024];
    biaskv[d * 2048 + part * 1024 + chunk * 256 + threadIdx.x] = acc;
}

__global__ __launch_bounds__(256)
void convert_bf16(const float* __restrict__ in, unsigned short* __restrict__ out, size_t n4)
{
    size_t i = (size_t)blockIdx.x * 256 + threadIdx.x;
    if (i >= n4) return;
    float4 v = ((const float4*)in)[i];
    ushort4 u;
    u.x = f2bf(v.x); u.y = f2bf(v.y); u.z = f2bf(v.z); u.w = f2bf(v.w);
    ((ushort4*)out)[i] = u;
}

__global__ __launch_bounds__(256)
void init_x(const float* __restrict__ lat, float* __restrict__ x)
{
    const int row = blockIdx.x;
    ((float4*)x)[(size_t)row * 256 + threadIdx.x] =
        ((const float4*)lat)[(size_t)(row & 255) * 256 + threadIdx.x];
}

// ---------------------------------------------------------------------------
// LayerNorm over D=1024, one row per block.
// ---------------------------------------------------------------------------
template<bool AFFINE, bool OUTBF>
__global__ __launch_bounds__(256)
void ln_k(const float* __restrict__ in, const float* __restrict__ g,
          const float* __restrict__ b, void* __restrict__ out)
{
    const int row = blockIdx.x;
    const int tid = threadIdx.x;
    float4 v = ((const float4*)(in + (size_t)row * 1024))[tid];
    float s  = v.x + v.y + v.z + v.w;
    float ss = v.x * v.x + v.y * v.y + v.z * v.z + v.w * v.w;
#pragma unroll
    for (int o = 32; o > 0; o >>= 1) { s += __shfl_down(s, o); ss += __shfl_down(ss, o); }
    __shared__ float red[8];
    if ((tid & 63) == 0) { red[tid >> 6] = s; red[4 + (tid >> 6)] = ss; }
    __syncthreads();
    const float sum  = red[0] + red[1] + red[2] + red[3];
    const float ssum = red[4] + red[5] + red[6] + red[7];
    const float mean = sum * (1.0f / 1024.0f);
    const float var  = ssum * (1.0f / 1024.0f) - mean * mean;
    const float rs   = rsqrtf(var + 1e-5f);
    float o0 = (v.x - mean) * rs, o1 = (v.y - mean) * rs;
    float o2 = (v.z - mean) * rs, o3 = (v.w - mean) * rs;
    if (AFFINE) {
        float4 gv = ((const float4*)g)[tid];
        float4 bv = ((const float4*)b)[tid];
        o0 = o0 * gv.x + bv.x; o1 = o1 * gv.y + bv.y;
        o2 = o2 * gv.z + bv.z; o3 = o3 * gv.w + bv.w;
    }
    if (OUTBF) {
        ushort4 u; u.x = f2bf(o0); u.y = f2bf(o1); u.z = f2bf(o2); u.w = f2bf(o3);
        ((ushort4*)out)[(size_t)row * 256 + tid] = u;
    } else {
        float4 ov; ov.x = o0; ov.y = o1; ov.z = o2; ov.w = o3;
        ((float4*)out)[(size_t)row * 256 + tid] = ov;
    }
}

enum { E_BF16 = 0, E_BIAS_BF16, E_BIAS_GELU_BF16, E_BIAS_TPOS_F32, E_ADD_F32, E_BIAS_ADD_F32 };

// ---------------------------------------------------------------------------
// Big-shape GEMM: 256x256, BK=64, 8 waves (2Mx4N), 128 KiB LDS double-buffer.
// Round-6 schedule: software-pipelined fragment reads (one phase ahead,
// alternating ax/ay register sets), counted lgkmcnt(4) + sched_barrier(0)
// (rule #18), 4 barriers/K-tile, counted vmcnt(4) at tile boundary only,
// next-tile mi0,1 prefetched before the last MFMA cluster.
// Zero-conflict 8-chunk XOR swizzle on staging source + reads (r4-verified).
// C(M,N) = A(M,K) @ Bt(N,K)^T. Requires M%256==0, N%256==0, K%64==0, grid%8==0.
// ---------------------------------------------------------------------------
template<int EPI>
__global__ __launch_bounds__(512, 2)
void g8p(const unsigned short* __restrict__ A, const unsigned short* __restrict__ Bt,
         void* __restrict__ Out,
         const float* __restrict__ bias, const float* __restrict__ tpos,
         int M, int N, int K)
{
    // layout (u16): A buf d: halves @ d*16384 + {0,8192}; B: 32768 + d*16384 + {0,8192}
    __shared__ unsigned short sm[65536];

    const int tid = threadIdx.x;
    const int wid = tid >> 6, lane = tid & 63;
    const int wm = wid >> 2, wn = wid & 3;

    const int nbx = N >> 8;
    const int nwg = gridDim.x;
    const int bid = blockIdx.x;
    const int wg = (bid & 7) * (nwg >> 3) + (bid >> 3);   // bijective, nwg%8==0
    const int by = wg / nbx, bx = wg % nbx;
    const int nt = K >> 6;

    const int srow = wid * 8 + (lane >> 3);               // 0..63
    const int schk = ((lane & 7) ^ (lane >> 3)) * 8;
    const unsigned short* gA = A  + (size_t)(by * 256 + srow) * K + schk;
    const unsigned short* gB = Bt + (size_t)(bx * 256 + srow) * K + schk;
    const int ldst = wid * 512;

    auto stgA = [&](int d, int h, int T) {
        const unsigned short* g = gA + (size_t)(h * 64) * K + (size_t)T * 64;
        unsigned short* l = sm + d * 16384 + h * 8192 + ldst;
        GLL16(g, l);
        GLL16(g + (size_t)128 * K, l + 4096);
    };
    auto stgB = [&](int d, int h, int T) {
        const unsigned short* g = gB + (size_t)(h * 128) * K + (size_t)T * 64;
        unsigned short* l = sm + 32768 + d * 16384 + h * 8192 + ldst;
        GLL16(g, l);
        GLL16(g + (size_t)64 * K, l + 4096);
    };

    const int q = lane >> 4;
    const int cks0 = ((q    ) ^ (lane & 7)) * 8;
    const int cks1 = ((q + 4) ^ (lane & 7)) * 8;
    const int arow = (wm * 64 + (lane & 15)) * 64;
    const int brow = ((wn & 1) * 64 + (lane & 15)) * 64;
    const int bhoff = 32768 + (wn >> 1) * 8192;

    f32x4 acc[8][4] = {};
    bf16x8 ax[2][2], ay[2][2], b[4][2];

#define READ_A(dst, base, HOFF, E0)                                                  \
    dst[0][0] = *(const bf16x8*)((base) + (HOFF) + arow + (E0) * 1024 + cks0);       \
    dst[0][1] = *(const bf16x8*)((base) + (HOFF) + arow + (E0) * 1024 + cks1);       \
    dst[1][0] = *(const bf16x8*)((base) + (HOFF) + arow + ((E0) + 1) * 1024 + cks0); \
    dst[1][1] = *(const bf16x8*)((base) + (HOFF) + arow + ((E0) + 1) * 1024 + cks1);

#define READ_Bm(Bb)                                                                  \
    _Pragma("unroll")                                                                \
    for (int ni = 0; ni < 4; ++ni) {                                                 \
        b[ni][0] = *(const bf16x8*)((Bb) + brow + ni * 1024 + cks0);                 \
        b[ni][1] = *(const bf16x8*)((Bb) + brow + ni * 1024 + cks1);                 \
    }

#define CLUST(R0, as)                                                                \
    __builtin_amdgcn_s_setprio(1);                                                   \
    _Pragma("unroll")                                                                \
    for (int e = 0; e < 2; ++e)                                                      \
        _Pragma("unroll")                                                            \
        for (int ni = 0; ni < 4; ++ni) {                                             \
            acc[(R0) + e][ni] = MF(as[e][0], b[ni][0], acc[(R0) + e][ni]);           \
            acc[(R0) + e][ni] = MF(as[e][1], b[ni][1], acc[(R0) + e][ni]);           \
        }                                                                            \
    __builtin_amdgcn_s_setprio(0);

    // ---- prologue: tile 0 fully staged; tile 1 B0,A0 in flight ----
    stgB(0, 0, 0); stgA(0, 0, 0); stgB(0, 1, 0); stgA(0, 1, 0);
    if (nt > 1) { stgB(1, 0, 1); stgA(1, 0, 1); }
    if (nt > 1) VMCNT(4); else VMCNT(0);
    BAR();
    READ_A(ax, sm, 0, 0);                       // tile0 mi0,1

    for (int T = 0; T < nt; ++T) {
        const int d = T & 1, dn = d ^ 1;
        const unsigned short* Ab  = sm + d * 16384;
        const unsigned short* Bb  = sm + bhoff + d * 16384;
        const unsigned short* AbN = sm + dn * 16384;
        const bool s1 = (T + 1 < nt), s2 = (T + 2 < nt);

        // ---- phase 0: M_0(mi0,1 | ax) ∥ reads{B, mi2,3→ay} ∥ stage T+1 B1,A1 ----
        if (s1) { stgB(dn, 1, T + 1); stgA(dn, 1, T + 1); }
        READ_Bm(Bb);
        READ_A(ay, Ab, 0, 2);
        LGKM(4);                                 // ax + B retired; ay in flight
        CLUST(0, ax);
        BAR();                                   // protects S1 (B0 of d was read by R_B)

        // ---- phase 1: M_1(mi2,3 | ay) ∥ read mi4,5→ax ∥ stage T+2 B0 ----
        if (s2) stgB(d, 0, T + 2);
        READ_A(ax, Ab, 8192, 0);
        LGKM(4);                                 // ay retired; ax in flight
        CLUST(2, ay);
        BAR();                                   // protects S2 (A0 of d read by ax/ay)

        // ---- phase 2: M_2(mi4,5 | ax) ∥ read mi6,7→ay ∥ stage T+2 A0 ----
        if (s2) stgA(d, 0, T + 2);
        READ_A(ay, Ab, 8192, 2);
        LGKM(4);                                 // ax retired; ay in flight
        CLUST(4, ax);

        // ---- phase 3: boundary certify + prefetch next mi0,1 ∥ M_3(mi6,7 | ay) ----
        if (s1) {
            if (s2) VMCNT(4); else VMCNT(0);     // T+1 fully landed
            BAR();                               // cross-wave GLL visibility
            READ_A(ax, AbN, 0, 0);               // next tile mi0,1
            LGKM(4);                             // ay retired; ax in flight
        } else {
            LGKM(0);                             // last tile: drain ay
        }
        CLUST(6, ay);
        BAR();                                   // protects next S0 (B1,A1 of dn)
    }
#undef READ_A
#undef READ_Bm
#undef CLUST

    // -------- epilogue: C/D layout col = lane&15, row = (lane>>4)*4 + reg --------
    const int r0 = by * 256 + wm * 128 + (lane >> 4) * 4;
    const int c0 = bx * 256 + wn * 64 + (lane & 15);
#pragma unroll
    for (int mi = 0; mi < 8; ++mi) {
#pragma unroll
        for (int ni = 0; ni < 4; ++ni) {
            const int c = c0 + ni * 16;
            float bv = 0.f;
            if (EPI == E_BIAS_BF16 || EPI == E_BIAS_GELU_BF16 || EPI == E_BIAS_TPOS_F32)
                bv = bias[c];
#pragma unroll
            for (int j = 0; j < 4; ++j) {
                const int r = r0 + mi * 16 + j;
                float v = acc[mi][ni][j] + bv;
                if (EPI == E_BIAS_GELU_BF16) v = gelu_exact(v);
                if (EPI == E_BIAS_TPOS_F32) {
                    v += tpos[(((unsigned)r >> 8) & 15) * 1024 + c];
                    ((float*)Out)[(size_t)r * N + c] = v;
                } else {
                    ((unsigned short*)Out)[(size_t)r * N + c] = f2bf(v);
                }
            }
        }
    }
}

// ---------------------------------------------------------------------------
// Latent-stack GEMM: 64x128 tile, BK=64, 4 waves, 24 KB LDS, m97 skeleton +
// zero-conflict swizzle (r4-verified).
// ---------------------------------------------------------------------------
template<int EPI>
__global__ __launch_bounds__(256, 4)
void gemm64(const unsigned short* __restrict__ A, const unsigned short* __restrict__ Bt,
            void* __restrict__ Out,
            const float* __restrict__ bias, const float* __restrict__ addsrc,
            int M, int N, int K)
{
    __shared__ unsigned short lds[64 * 64 + 128 * 64];
    const int tid  = threadIdx.x;
    const int wave = tid >> 6, lane = tid & 63;
    const int nbx  = N >> 7;

    const int nwg = gridDim.x;
    int bid = blockIdx.x;
    int wg = ((nwg & 7) == 0) ? ((bid & 7) * (nwg >> 3) + (bid >> 3)) : bid;
    const int by = wg / nbx, bx = wg % nbx;

    const int swz = ((lane & 7) ^ (lane >> 3)) * 8;
    const unsigned short* gA = A  + (size_t)(by * 64  + (lane >> 3)) * K + swz;
    const unsigned short* gB = Bt + (size_t)(bx * 128 + (lane >> 3)) * K + swz;

    const int wr = wave >> 1, wc = wave & 1;
    f32x4 acc[2][4] = {};

    unsigned short* ldsA = lds;
    unsigned short* ldsB = lds + 64 * 64;

    const int off0 = (((lane >> 4)    ) ^ (lane & 7)) * 8;
    const int off1 = (((lane >> 4) | 4) ^ (lane & 7)) * 8;
    const unsigned short* la = ldsA + (wr * 32 + (lane & 15)) * 64;
    const unsigned short* lb = ldsB + (wc * 64 + (lane & 15)) * 64;

    for (int kt = 0; kt < K; kt += 64) {
        GLL16(gA + (size_t)(wave)     * 8 * K + kt, ldsA + (wave)      * 512);
        GLL16(gA + (size_t)(4 + wave) * 8 * K + kt, ldsA + (4 + wave)  * 512);
#pragma unroll
        for (int j = 0; j < 4; ++j) {
            const int chunk = (j << 2) + wave;
            GLL16(gB + (size_t)chunk * 8 * K + kt, ldsB + chunk * 512);
        }
        __syncthreads();
#pragma unroll
        for (int kk = 0; kk < 2; ++kk) {
            const int offk = kk ? off1 : off0;
            bf16x8 a[2], b[4];
#pragma unroll
            for (int m = 0; m < 2; ++m) a[m] = *(const bf16x8*)(la + m * 1024 + offk);
#pragma unroll
            for (int n = 0; n < 4; ++n) b[n] = *(const bf16x8*)(lb + n * 1024 + offk);
#pragma unroll
            for (int m = 0; m < 2; ++m)
#pragma unroll
                for (int n = 0; n < 4; ++n)
                    acc[m][n] = __builtin_amdgcn_mfma_f32_16x16x32_bf16(a[m], b[n], acc[m][n], 0, 0, 0);
        }
        __syncthreads();
    }

    const int r0 = by * 64 + wr * 32 + (lane >> 4) * 4;
    const int c0 = bx * 128 + wc * 64 + (lane & 15);
#pragma unroll
    for (int m = 0; m < 2; ++m) {
#pragma unroll
        for (int n = 0; n < 4; ++n) {
            const int c = c0 + n * 16;
#pragma unroll
            for (int j = 0; j < 4; ++j) {
                const int r = r0 + m * 16 + j;
                float v = acc[m][n][j];
                if (EPI == E_BIAS_BF16 || EPI == E_BIAS_GELU_BF16 || EPI == E_BIAS_ADD_F32)
                    v += bias[c];
                if (EPI == E_BIAS_GELU_BF16) v = gelu_exact(v);
                if (EPI == E_ADD_F32 || EPI == E_BIAS_ADD_F32) v += addsrc[(size_t)r * N + c];
                if (EPI == E_ADD_F32 || EPI == E_BIAS_ADD_F32)
                    ((float*)Out)[(size_t)r * N + c] = v;
                else
                    ((unsigned short*)Out)[(size_t)r * N + c] = f2bf(v);
            }
        }
    }
}

// ---------------------------------------------------------------------------
// Attention: one block per (bt, head). Q=16, F=272, DH=64.
// ---------------------------------------------------------------------------
__global__ __launch_bounds__(256)
void attn_k(const unsigned short* __restrict__ qkvl, const unsigned short* __restrict__ kvm,
            unsigned short* __restrict__ o)
{
    __shared__ unsigned short kv[272 * 72];
    __shared__ float sim[16 * 273];
    __shared__ float qs[16 * 68];
    __shared__ float red[64];

    const int bt = blockIdx.x >> 4, h = blockIdx.x & 15;
    const int tid = threadIdx.x;
    const int lane = tid & 63, wave = tid >> 6;
    const int r = tid & 15, grp = tid >> 4;

    {
        const int qi = tid >> 4, d0 = (tid & 15) * 4;
        const unsigned short* src = qkvl + (size_t)(bt * 16 + qi) * 3072 + h * 64 + d0;
        qs[qi * 68 + d0 + 0] = bf2f(src[0]);
        qs[qi * 68 + d0 + 1] = bf2f(src[1]);
        qs[qi * 68 + d0 + 2] = bf2f(src[2]);
        qs[qi * 68 + d0 + 3] = bf2f(src[3]);
    }
#pragma unroll
    for (int i = 0; i < 9; ++i) {
        int idx = i * 256 + tid;
        if (idx < 2176) {
            int f = idx >> 3, cp = idx & 7;
            const unsigned short* src = (f < 256)
                ? kvm  + (size_t)(bt * 256 + f) * 2048 + h * 64 + cp * 8
                : qkvl + (size_t)(bt * 16 + (f - 256)) * 3072 + 1024 + h * 64 + cp * 8;
            *(short8*)&kv[f * 72 + cp * 8] = *(const short8*)src;
        }
    }
    __syncthreads();

    float p[17];
#pragma unroll
    for (int i = 0; i < 17; ++i) p[i] = 0.f;
#pragma unroll
    for (int d = 0; d < 64; d += 8) {
        float q8[8];
#pragma unroll
        for (int j = 0; j < 8; ++j) q8[j] = qs[r * 68 + d + j];
#pragma unroll
        for (int i = 0; i < 17; ++i) {
            short8 k8 = *(const short8*)&kv[(grp + i * 16) * 72 + d];
#pragma unroll
            for (int j = 0; j < 8; ++j) p[i] += q8[j] * bf2f((unsigned short)k8[j]);
        }
    }
    float mx = -3.0e38f;
#pragma unroll
    for (int i = 0; i < 17; ++i) mx = fmaxf(mx, p[i]);
    mx = fmaxf(mx, __shfl_xor(mx, 16));
    mx = fmaxf(mx, __shfl_xor(mx, 32));
    if (lane < 16) red[wave * 16 + lane] = mx;
    __syncthreads();
    const float rowmax = fmaxf(fmaxf(red[r], red[16 + r]), fmaxf(red[32 + r], red[48 + r]));

    float sm = 0.f;
#pragma unroll
    for (int i = 0; i < 17; ++i) { p[i] = __expf(p[i] - rowmax); sm += p[i]; }
    sm += __shfl_xor(sm, 16);
    sm += __shfl_xor(sm, 32);
#pragma unroll
    for (int i = 0; i < 17; ++i) sim[r * 273 + grp + i * 16] = p[i];
    __syncthreads();
    if (lane < 16) red[wave * 16 + lane] = sm;
#pragma unroll
    for (int i = 0; i < 9; ++i) {
        int idx = i * 256 + tid;
        if (idx < 2176) {
            int f = idx >> 3, cp = idx & 7;
            const unsigned short* src = (f < 256)
                ? kvm  + (size_t)(bt * 256 + f) * 2048 + 1024 + h * 64 + cp * 8
                : qkvl + (size_t)(bt * 16 + (f - 256)) * 3072 + 2048 + h * 64 + cp * 8;
            *(short8*)&kv[f * 72 + cp * 8] = *(const short8*)src;
        }
    }
    __syncthreads();
    const float inv = 1.0f / (red[r] + red[16 + r] + red[32 + r] + red[48 + r]);

    float o0 = 0.f, o1 = 0.f, o2 = 0.f, o3 = 0.f;
    for (int f = 0; f < 272; ++f) {
        float pv = sim[r * 273 + f];
        short4v v4 = *(const short4v*)&kv[f * 72 + grp * 4];
        o0 += pv * bf2f((unsigned short)v4[0]);
        o1 += pv * bf2f((unsigned short)v4[1]);
        o2 += pv * bf2f((unsigned short)v4[2]);
        o3 += pv * bf2f((unsigned short)v4[3]);
    }
    unsigned short* dst = o + (size_t)(bt * 16 + r) * 1024 + h * 64 + grp * 4;
    dst[0] = f2bf(o0 * inv);
    dst[1] = f2bf(o1 * inv);
    dst[2] = f2bf(o2 * inv);
    dst[3] = f2bf(o3 * inv);
}

// ---------------------------------------------------------------------------
extern "C" void kernel_launch(void* const* d_in, const int* in_sizes, int n_in,
                              void* d_out, int out_size, void* d_ws, size_t ws_size,
                              hipStream_t stream)
{
    const float* x_f      = (const float*)d_in[0];
    const float* goal_w1  = (const float*)d_in[1];
    const float* goal_b1  = (const float*)d_in[2];
    const float* goal_w2  = (const float*)d_in[3];
    const float* goal_b2  = (const float*)d_in[4];
    const float* latents  = (const float*)d_in[5];
    const float* tpos     = (const float*)d_in[6];
    const float* lnm_g    = (const float*)d_in[7];
    const float* lnm_b    = (const float*)d_in[8];
    const float* lnl_g    = (const float*)d_in[9];
    const float* lnl_b    = (const float*)d_in[10];
    const float* wq       = (const float*)d_in[11];
    const float* wk       = (const float*)d_in[12];
    const float* wv       = (const float*)d_in[13];
    const float* wo       = (const float*)d_in[14];
    const float* ffn_g    = (const float*)d_in[15];
    const float* ffn_b    = (const float*)d_in[16];
    const float* ffw1     = (const float*)d_in[17];
    const float* ffb1     = (const float*)d_in[18];
    const float* ffw2     = (const float*)d_in[19];
    const float* ffb2     = (const float*)d_in[20];
    const float* fin_g    = (const float*)d_in[21];
    const float* fin_b    = (const float*)d_in[22];

    char* ws = (char*)d_ws;
    size_t off = 0;
    auto alloc = [&](size_t bytes) -> char* {
        char* p = ws + off;
        off += (bytes + 255) & ~(size_t)255;
        return p;
    };
    typedef unsigned short u16;
    u16*   wg1t   = (u16*)  alloc(2048ull * 1280 * 2);
    u16*   wg2t   = (u16*)  alloc(1024ull * 2048 * 2);
    u16*   wqkvl  = (u16*)  alloc(6ull * 3072 * 1024 * 2);
    u16*   wkvm   = (u16*)  alloc(6ull * 2048 * 1024 * 2);
    u16*   wot    = (u16*)  alloc(6ull * 1024 * 1024 * 2);
    u16*   wf1t   = (u16*)  alloc(6ull * 4096 * 1024 * 2);
    u16*   wf2t   = (u16*)  alloc(6ull * 1024 * 4096 * 2);
    float* biaskv = (float*)alloc(6ull * 2048 * 4);
    float* xres   = (float*)alloc(2048ull * 1024 * 4);
    u16*   latn   = (u16*)  alloc(2048ull * 1024 * 2);
    u16*   qkvl   = (u16*)  alloc(2048ull * 3072 * 2);
    u16*   obuf   = (u16*)  alloc(2048ull * 1024 * 2);
    u16*   ffny   = (u16*)  alloc(2048ull * 1024 * 2);
    u16*   ffnmid = (u16*)  alloc(2048ull * 4096 * 2);
    u16*   bufA   = (u16*)  alloc(32768ull * 2048 * 2);
    float* bufB   = (float*)alloc(32768ull * 1024 * 4);
    u16*   bufC   = (u16*)  alloc(41943040ull * 2);
    if (off > ws_size) return;

    // ---- phase 0: conversions / folds ----
    convert_bf16<<<40960, 256, 0, stream>>>(x_f, bufC, 41943040ull / 4);
    transpose_w<<<dim3(32, 20, 1), 256, 0, stream>>>(goal_w1, wg1t, nullptr, 1.f, 1280, 2048, 0, 0, 0);
    transpose_w<<<dim3(16, 32, 1), 256, 0, stream>>>(goal_w2, wg2t, nullptr, 1.f, 2048, 1024, 0, 0, 0);
    transpose_w<<<dim3(16, 16, 6), 256, 0, stream>>>(wq, wqkvl,                nullptr, 0.125f, 1024, 1024, 1024ull*1024, 3072ull*1024, 0);
    transpose_w<<<dim3(16, 16, 6), 256, 0, stream>>>(wk, wqkvl + 1024ull*1024, nullptr, 1.f,    1024, 1024, 1024ull*1024, 3072ull*1024, 0);
    transpose_w<<<dim3(16, 16, 6), 256, 0, stream>>>(wv, wqkvl + 2048ull*1024, nullptr, 1.f,    1024, 1024, 1024ull*1024, 3072ull*1024, 0);
    transpose_w<<<dim3(16, 16, 6), 256, 0, stream>>>(wk, wkvm,                 lnm_g,   1.f,    1024, 1024, 1024ull*1024, 2048ull*1024, 1024);
    transpose_w<<<dim3(16, 16, 6), 256, 0, stream>>>(wv, wkvm + 1024ull*1024,  lnm_g,   1.f,    1024, 1024, 1024ull*1024, 2048ull*1024, 1024);
    transpose_w<<<dim3(16, 16, 6), 256, 0, stream>>>(wo, wot,                  nullptr, 1.f,    1024, 1024, 1024ull*1024, 1024ull*1024, 0);
    transpose_w<<<dim3(64, 16, 6), 256, 0, stream>>>(ffw1, wf1t,               nullptr, 1.f,    1024, 4096, 4096ull*1024, 4096ull*1024, 0);
    transpose_w<<<dim3(16, 64, 6), 256, 0, stream>>>(ffw2, wf2t,               nullptr, 1.f,    4096, 1024, 4096ull*1024, 4096ull*1024, 0);
    fold_bias<<<48, 256, 0, stream>>>(wk, wv, lnm_b, biaskv);
    init_x<<<2048, 256, 0, stream>>>(latents, xres);

    // ---- goal MLP (8-phase 256^2) ----
    g8p<E_BIAS_GELU_BF16><<<1024, 512, 0, stream>>>(bufC, wg1t, bufA, goal_b1, nullptr, 32768, 2048, 1280);
    g8p<E_BIAS_TPOS_F32><<<512, 512, 0, stream>>>(bufA, wg2t, bufB, goal_b2, tpos, 32768, 1024, 2048);
    ln_k<false, true><<<32768, 256, 0, stream>>>(bufB, nullptr, nullptr, bufC);

    // ---- depth loop ----
    for (int i = 0; i < 6; ++i) {
        const u16* wqkvl_i = wqkvl + (size_t)i * 3072 * 1024;
        const u16* wkvm_i  = wkvm  + (size_t)i * 2048 * 1024;
        const u16* wot_i   = wot   + (size_t)i * 1024 * 1024;
        const u16* wf1_i   = wf1t  + (size_t)i * 4096 * 1024;
        const u16* wf2_i   = wf2t  + (size_t)i * 1024 * 4096;

        ln_k<true, true><<<2048, 256, 0, stream>>>(xres, lnl_g + i * 1024, lnl_b + i * 1024, latn);
        gemm64<E_BF16><<<32 * 24, 256, 0, stream>>>(latn, wqkvl_i, qkvl, nullptr, nullptr, 2048, 3072, 1024);
        g8p<E_BIAS_BF16><<<1024, 512, 0, stream>>>(bufC, wkvm_i, bufA, biaskv + i * 2048, nullptr, 32768, 2048, 1024);
        attn_k<<<2048, 256, 0, stream>>>(qkvl, bufA, obuf);
        gemm64<E_ADD_F32><<<32 * 8, 256, 0, stream>>>(obuf, wot_i, xres, nullptr, xres, 2048, 1024, 1024);
        ln_k<true, true><<<2048, 256, 0, stream>>>(xres, ffn_g + i * 1024, ffn_b + i * 1024, ffny);
        gemm64<E_BIAS_GELU_BF16><<<32 * 32, 256, 0, stream>>>(ffny, wf1_i, ffnmid, ffb1 + i * 4096, nullptr, 2048, 4096, 1024);
        gemm64<E_BIAS_ADD_F32><<<32 * 8, 256, 0, stream>>>(ffnmid, wf2_i, xres, ffb2 + i * 1024, xres, 2048, 1024, 4096);
    }

    // ---- final LN -> d_out (f32) ----
    ln_k<true, false><<<2048, 256, 0, stream>>>(xres, fin_g, fin_b, d_out);
}